// Round 11
// baseline (212.747 us; speedup 1.0000x reference)
//
#include <hip/hip_runtime.h>
#include <hip/hip_bf16.h>
#include <stdint.h>
#include <stddef.h>

// MultiHA: y@Wq^T -> q; x@Wk^T -> k; x@Wv^T -> v; causal softmax attn; @Wp^T + bp
// B=4 S=2048 D=1024 NH=16 HS=64. All GEMM/attn compute in bf16 MFMA, f32 accum.

typedef __attribute__((ext_vector_type(4))) float f32x4;
typedef __attribute__((ext_vector_type(8))) short s16x8;
typedef __attribute__((ext_vector_type(4))) float float4v;
typedef __attribute__((ext_vector_type(4))) int i32x4;
typedef __attribute__((ext_vector_type(2))) unsigned int u32x2;

#define DEV __device__ __forceinline__

constexpr int Bsz = 4, Sseq = 2048, Dm = 1024, NHn = 16, HSn = 64;
// fold 1/sqrt(HS) * log2(e) into Wq so attention softmax runs in exp2 domain
constexpr float QSCALE = 0.125f * 1.4426950408889634f;

// ---- workspace layout (bytes) ----
constexpr size_t SZ_BF_XY = (size_t)Bsz * Sseq * Dm * 2;  // 16 MiB
constexpr size_t SZ_W     = (size_t)Dm * Dm * 2;          // 2 MiB
constexpr size_t OFF_XBF  = 0;
constexpr size_t OFF_YBF  = OFF_XBF + SZ_BF_XY;
constexpr size_t OFF_WQ   = OFF_YBF + SZ_BF_XY;
constexpr size_t OFF_WK   = OFF_WQ + SZ_W;
constexpr size_t OFF_WV   = OFF_WK + SZ_W;
constexpr size_t OFF_WP   = OFF_WV + SZ_W;
constexpr size_t OFF_QWS  = OFF_WP + SZ_W;   // [BH][S][64] bf16
constexpr size_t OFF_KWS  = OFF_QWS + SZ_BF_XY;
constexpr size_t OFF_VTWS = OFF_KWS + SZ_BF_XY; // [BH][64][S] bf16 (V transposed)
constexpr size_t OFF_OWS  = OFF_VTWS + SZ_BF_XY; // attn out [B][S][D] bf16
constexpr size_t OFF_FLAG = OFF_OWS + SZ_BF_XY;

DEV unsigned short f2bf(float f) {
  union { float f; unsigned int u; } v; v.f = f;
  unsigned int r = (v.u + 0x7FFFu + ((v.u >> 16) & 1u)) >> 16;
  return (unsigned short)r;
}

DEV void gll16(const void* g, void* l) {
  __builtin_amdgcn_global_load_lds((const __attribute__((address_space(1))) unsigned int*)g,
                                   (__attribute__((address_space(3))) unsigned int*)l, 16, 0, 0);
}

DEV unsigned int cvtpk(float a, float b) {
  unsigned int r;
  asm("v_cvt_pk_bf16_f32 %0, %1, %2" : "=v"(r) : "v"(a), "v"(b));
  return r;
}

// ------ fused fp32->bf16 conversion of all inputs + pad/tmask triviality check ------
__global__ void cvt_all(const float* __restrict__ x, const float* __restrict__ y,
                        const float* __restrict__ Wq, const float* __restrict__ Wk,
                        const float* __restrict__ Wv, const float* __restrict__ Wp,
                        const int* __restrict__ pad, const int* __restrict__ tmask,
                        char* __restrict__ ws, int* __restrict__ flags) {
  const int blk = blockIdx.x;
  if (blk >= 10240) {
    int bad = 0;
    if (blk < 10248) { // pad: 8192 ints, 4 per thread
      const i32x4 v = ((const i32x4*)pad)[(blk - 10240) * 256 + threadIdx.x];
      bad = (v[0] == 0) | (v[1] == 0) | (v[2] == 0) | (v[3] == 0);
    } else { // tmask: 4M ints, 8 per thread
      const i32x4* tp = (const i32x4*)tmask + ((size_t)(blk - 10248) * 256 + threadIdx.x) * 2;
      i32x4 v0 = tp[0], v1 = tp[1];
      bad = (v0[0] == 0) | (v0[1] == 0) | (v0[2] == 0) | (v0[3] == 0) |
            (v1[0] == 0) | (v1[1] == 0) | (v1[2] == 0) | (v1[3] == 0);
    }
    if (__builtin_amdgcn_ballot_w64(bad) != 0 && (threadIdx.x & 63) == 0)
      atomicOr(flags, 1);
    return;
  }
  const float* src;
  unsigned short* dst;
  int b8;
  float scale = 1.f;
  if (blk < 4096)      { src = x;  dst = (unsigned short*)(ws + OFF_XBF); b8 = blk; }
  else if (blk < 8192) { src = y;  dst = (unsigned short*)(ws + OFF_YBF); b8 = blk - 4096; }
  else if (blk < 8704) { src = Wq; dst = (unsigned short*)(ws + OFF_WQ);  b8 = blk - 8192; scale = QSCALE; }
  else if (blk < 9216) { src = Wk; dst = (unsigned short*)(ws + OFF_WK);  b8 = blk - 8704; }
  else if (blk < 9728) { src = Wv; dst = (unsigned short*)(ws + OFF_WV);  b8 = blk - 9216; }
  else                 { src = Wp; dst = (unsigned short*)(ws + OFF_WP);  b8 = blk - 9728; }
  const size_t i = (size_t)b8 * 256 + threadIdx.x;
  const float4v* s = (const float4v*)src + i * 2;
  float4v a = s[0], b = s[1];
  s16x8 o;
  o[0] = (short)f2bf(a[0] * scale); o[1] = (short)f2bf(a[1] * scale);
  o[2] = (short)f2bf(a[2] * scale); o[3] = (short)f2bf(a[3] * scale);
  o[4] = (short)f2bf(b[0] * scale); o[5] = (short)f2bf(b[1] * scale);
  o[6] = (short)f2bf(b[2] * scale); o[7] = (short)f2bf(b[3] * scale);
  *(s16x8*)(dst + i * 8) = o;
}

// ---------------- Q projection GEMM (2-phase double-buffered staging) ----------------
__global__ __launch_bounds__(256) void q_gemm(const unsigned short* __restrict__ A,
                                              const unsigned short* __restrict__ W,
                                              unsigned short* __restrict__ outb) {
  constexpr int K = 1024;
  __shared__ unsigned short sm[2][8192]; // [buf][lA 4096 | lB 4096]
  const int tid = threadIdx.x;
  const int w = tid >> 6, lane = tid & 63, lo = lane & 15, hi = lane >> 4;
  const int wm = w >> 1, wn = w & 1;
  const int m0 = blockIdx.x * 128, n0 = blockIdx.y * 128;
  f32x4 acc[4][4] = {};

  auto stage = [&](int buf, int k0) {
#pragma unroll
    for (int h = 0; h < 2; ++h) {
      int c = w * 64 + h * 256 + lane;
      gll16(A + (size_t)(m0 + (c >> 2)) * K + k0 + (c & 3) * 8, &sm[buf][0] + (size_t)(w * 64 + h * 256) * 8);
      gll16(W + (size_t)(n0 + (c >> 2)) * K + k0 + (c & 3) * 8, &sm[buf][4096] + (size_t)(w * 64 + h * 256) * 8);
    }
  };

  stage(0, 0);
  __syncthreads(); // drains vmcnt -> buf0 ready
  for (int t = 0; t < 32; ++t) {
    if (t < 31) stage((t + 1) & 1, (t + 1) * 32); // issue next tile early
    const unsigned short* lA = &sm[t & 1][0];
    const unsigned short* lB = &sm[t & 1][4096];
    s16x8 af[4], bfr[4];
#pragma unroll
    for (int mi = 0; mi < 4; ++mi) af[mi] = *(const s16x8*)&lA[(wm * 64 + mi * 16 + lo) * 32 + hi * 8];
#pragma unroll
    for (int ni = 0; ni < 4; ++ni) bfr[ni] = *(const s16x8*)&lB[(wn * 64 + ni * 16 + lo) * 32 + hi * 8];
#pragma unroll
    for (int mi = 0; mi < 4; ++mi)
#pragma unroll
      for (int ni = 0; ni < 4; ++ni)
        acc[mi][ni] = __builtin_amdgcn_mfma_f32_16x16x32_bf16(af[mi], bfr[ni], acc[mi][ni], 0, 0, 0);
    __syncthreads(); // readers done + next-tile loads drained
  }
#pragma unroll
  for (int mi = 0; mi < 4; ++mi)
#pragma unroll
    for (int ni = 0; ni < 4; ++ni)
#pragma unroll
      for (int j = 0; j < 4; ++j) {
        int m = m0 + wm * 64 + mi * 16 + hi * 4 + j;
        int n = n0 + wn * 64 + ni * 16 + lo;
        int b = m >> 11, s = m & 2047, hh = n >> 6, e = n & 63;
        outb[((size_t)(b * NHn + hh) * Sseq + s) * HSn + e] = f2bf(acc[mi][ni][j]);
      }
}

// -------- merged K+V projection GEMM (shared x staging, 2-phase double-buffer) --------
__global__ __launch_bounds__(256, 2) void kv_gemm(const unsigned short* __restrict__ A,
                                                  const unsigned short* __restrict__ Wk,
                                                  const unsigned short* __restrict__ Wv,
                                                  unsigned short* __restrict__ kws,
                                                  unsigned short* __restrict__ vtw) {
  constexpr int K = 1024;
  __shared__ unsigned short sm[2][12288]; // [buf][lA | lBk | lBv]; epilogue reuses flat
  const int tid = threadIdx.x;
  const int w = tid >> 6, lane = tid & 63, lo = lane & 15, hi = lane >> 4;
  const int wm = w >> 1, wn = w & 1;
  const int m0 = blockIdx.x * 128, n0 = blockIdx.y * 128;
  f32x4 acck[4][4] = {}, accv[4][4] = {};

  auto stage = [&](int buf, int k0) {
#pragma unroll
    for (int h = 0; h < 2; ++h) {
      int c = w * 64 + h * 256 + lane;
      size_t roff = (size_t)(c >> 2) * K + k0 + (c & 3) * 8;
      size_t loff = (size_t)(w * 64 + h * 256) * 8;
      gll16(A + (size_t)m0 * K + roff, &sm[buf][0] + loff);
      gll16(Wk + (size_t)n0 * K + roff, &sm[buf][4096] + loff);
      gll16(Wv + (size_t)n0 * K + roff, &sm[buf][8192] + loff);
    }
  };

  stage(0, 0);
  __syncthreads();
  for (int t = 0; t < 32; ++t) {
    if (t < 31) stage((t + 1) & 1, (t + 1) * 32);
    const unsigned short* lA = &sm[t & 1][0];
    const unsigned short* lBk = &sm[t & 1][4096];
    const unsigned short* lBv = &sm[t & 1][8192];
    s16x8 af[4], bfk[4], bfv[4];
#pragma unroll
    for (int mi = 0; mi < 4; ++mi) af[mi] = *(const s16x8*)&lA[(wm * 64 + mi * 16 + lo) * 32 + hi * 8];
#pragma unroll
    for (int ni = 0; ni < 4; ++ni) {
      bfk[ni] = *(const s16x8*)&lBk[(wn * 64 + ni * 16 + lo) * 32 + hi * 8];
      bfv[ni] = *(const s16x8*)&lBv[(wn * 64 + ni * 16 + lo) * 32 + hi * 8];
    }
#pragma unroll
    for (int mi = 0; mi < 4; ++mi)
#pragma unroll
      for (int ni = 0; ni < 4; ++ni) {
        acck[mi][ni] = __builtin_amdgcn_mfma_f32_16x16x32_bf16(af[mi], bfk[ni], acck[mi][ni], 0, 0, 0);
        accv[mi][ni] = __builtin_amdgcn_mfma_f32_16x16x32_bf16(af[mi], bfv[ni], accv[mi][ni], 0, 0, 0);
      }
    __syncthreads();
  }

  // K epilogue: direct global stores
#pragma unroll
  for (int mi = 0; mi < 4; ++mi)
#pragma unroll
    for (int ni = 0; ni < 4; ++ni)
#pragma unroll
      for (int j = 0; j < 4; ++j) {
        int m = m0 + wm * 64 + mi * 16 + hi * 4 + j;
        int n = n0 + wn * 64 + ni * 16 + lo;
        int b = m >> 11, s = m & 2047, hh = n >> 6, e = n & 63;
        kws[((size_t)(b * NHn + hh) * Sseq + s) * HSn + e] = f2bf(acck[mi][ni][j]);
      }
  // V epilogue: LDS transpose (reuses sm flat: needs 17408 shorts < 24576)
  unsigned short* tp = &sm[0][0];
  __syncthreads();
#pragma unroll
  for (int mi = 0; mi < 4; ++mi)
#pragma unroll
    for (int ni = 0; ni < 4; ++ni)
#pragma unroll
      for (int j = 0; j < 4; ++j) {
        int ml = wm * 64 + mi * 16 + hi * 4 + j;
        int nl = wn * 64 + ni * 16 + lo;
        tp[(size_t)nl * 136 + ml] = f2bf(accv[mi][ni][j]);
      }
  __syncthreads();
  int nl = tid >> 1, half = tid & 1;
  int b = m0 >> 11, hh = (n0 + nl) >> 6, e = (n0 + nl) & 63;
  unsigned short* dst = vtw + ((size_t)(b * NHn + hh) * HSn + e) * Sseq + (m0 & 2047) + half * 64;
#pragma unroll
  for (int i = 0; i < 8; ++i)
    *(s16x8*)(dst + i * 8) = *(const s16x8*)&tp[(size_t)nl * 136 + half * 64 + i * 8];
}

// ---------------- final projection GEMM (2-phase): fp32 out [M][1024] + bias ----------
__global__ __launch_bounds__(256) void gemm_p(const unsigned short* __restrict__ A,
                                              const unsigned short* __restrict__ W,
                                              float* __restrict__ outf,
                                              const float* __restrict__ bias) {
  constexpr int K = 1024;
  __shared__ unsigned short sm[2][8192];
  const int tid = threadIdx.x;
  const int w = tid >> 6, lane = tid & 63, lo = lane & 15, hi = lane >> 4;
  const int wm = w >> 1, wn = w & 1;
  const int m0 = blockIdx.x * 128, n0 = blockIdx.y * 128;
  f32x4 acc[4][4] = {};

  auto stage = [&](int buf, int k0) {
#pragma unroll
    for (int h = 0; h < 2; ++h) {
      int c = w * 64 + h * 256 + lane;
      gll16(A + (size_t)(m0 + (c >> 2)) * K + k0 + (c & 3) * 8, &sm[buf][0] + (size_t)(w * 64 + h * 256) * 8);
      gll16(W + (size_t)(n0 + (c >> 2)) * K + k0 + (c & 3) * 8, &sm[buf][4096] + (size_t)(w * 64 + h * 256) * 8);
    }
  };

  stage(0, 0);
  __syncthreads();
  for (int t = 0; t < 32; ++t) {
    if (t < 31) stage((t + 1) & 1, (t + 1) * 32);
    const unsigned short* lA = &sm[t & 1][0];
    const unsigned short* lB = &sm[t & 1][4096];
    s16x8 af[4], bfr[4];
#pragma unroll
    for (int mi = 0; mi < 4; ++mi) af[mi] = *(const s16x8*)&lA[(wm * 64 + mi * 16 + lo) * 32 + hi * 8];
#pragma unroll
    for (int ni = 0; ni < 4; ++ni) bfr[ni] = *(const s16x8*)&lB[(wn * 64 + ni * 16 + lo) * 32 + hi * 8];
#pragma unroll
    for (int mi = 0; mi < 4; ++mi)
#pragma unroll
      for (int ni = 0; ni < 4; ++ni)
        acc[mi][ni] = __builtin_amdgcn_mfma_f32_16x16x32_bf16(af[mi], bfr[ni], acc[mi][ni], 0, 0, 0);
    __syncthreads();
  }
  float bv[4];
#pragma unroll
  for (int ni = 0; ni < 4; ++ni) bv[ni] = bias[n0 + wn * 64 + ni * 16 + lo];
#pragma unroll
  for (int mi = 0; mi < 4; ++mi)
#pragma unroll
    for (int ni = 0; ni < 4; ++ni)
#pragma unroll
      for (int j = 0; j < 4; ++j) {
        int m = m0 + wm * 64 + mi * 16 + hi * 4 + j;
        int n = n0 + wn * 64 + ni * 16 + lo;
        outf[(size_t)m * 1024 + n] = acc[mi][ni][j] + bv[ni];
      }
}

// ---------------- flash attention (8-wave, dual-column units sharing K/V frags) -------
// Grid (8,64) = 512 blocks = 2/CU, 512 threads = 8 waves -> 16 waves/CU.
// Block (ip,bh): q-tiles qtA=ip, qtB=15-ip; wave w owns 16 rows of EACH tile; per kt
// the two columns' QK^T and PV share each kfr/vfr LDS read (one read, two MFMAs).
// st[t][j] = S[kpos=k0+t*16+hi*4+j][q=qw0+lo]; oacc[et][j] = O^T[e=et*16+hi*4+j][q].
// Defer-max (thr=11 in exp2 domain) + l via ones-MFMA (R9-verified).
DEV void softmax_col(f32x4 (&st)[4], int k0, int qw0, int lo, int hi, int b,
                     const int* __restrict__ pad, const int* __restrict__ tmask,
                     bool trivial, float& mrun, f32x4 (&oacc)[4], f32x4& lacc,
                     unsigned short* __restrict__ pbw) {
  const int qg = qw0 + lo;
  if (k0 + 63 > qw0) { // diagonal tiles: causal mask (kpos > q)
#pragma unroll
    for (int t = 0; t < 4; ++t)
#pragma unroll
      for (int j = 0; j < 4; ++j)
        if (k0 + t * 16 + hi * 4 + j > qg) st[t][j] = -3e38f;
  }
  if (!trivial) { // general pad/time masks (not hit for all-ones inputs)
#pragma unroll
    for (int t = 0; t < 4; ++t)
#pragma unroll
      for (int j = 0; j < 4; ++j) {
        int kg = k0 + t * 16 + hi * 4 + j;
        if (!pad[b * Sseq + kg] || !tmask[(size_t)qg * Sseq + kg]) st[t][j] = -3e38f;
      }
  }
  float m0v = fmaxf(fmaxf(st[0][0], st[0][1]), fmaxf(st[0][2], st[0][3]));
  float m1v = fmaxf(fmaxf(st[1][0], st[1][1]), fmaxf(st[1][2], st[1][3]));
  float m2v = fmaxf(fmaxf(st[2][0], st[2][1]), fmaxf(st[2][2], st[2][3]));
  float m3v = fmaxf(fmaxf(st[3][0], st[3][1]), fmaxf(st[3][2], st[3][3]));
  float mx = fmaxf(fmaxf(m0v, m1v), fmaxf(m2v, m3v));
  mx = fmaxf(mx, __shfl_xor(mx, 16, 64));
  mx = fmaxf(mx, __shfl_xor(mx, 32, 64));
  if (!__all(mx <= mrun + 11.f)) { // defer-max: rescale only when bound exceeded
    const float mnew = fmaxf(mrun, mx);
    const float al = __builtin_amdgcn_exp2f(mrun - mnew);
    mrun = mnew;
#pragma unroll
    for (int et = 0; et < 4; ++et) oacc[et] *= al;
    lacc *= al;
  }
#pragma unroll
  for (int t = 0; t < 4; ++t)
#pragma unroll
    for (int j = 0; j < 4; ++j)
      st[t][j] = __builtin_amdgcn_exp2f(st[t][j] - mrun);
#pragma unroll
  for (int t = 0; t < 4; ++t) {
    u32x2 dd = {cvtpk(st[t][0], st[t][1]), cvtpk(st[t][2], st[t][3])};
    *(u32x2*)&pbw[lo * 72 + t * 16 + hi * 4] = dd;
  }
}

// normalize by l (lane-local) and write O via per-wave LDS transpose (16 rows)
DEV void attn_epi16(f32x4 (&oacc)[4], float lrun,
                    unsigned short* __restrict__ pbw,
                    unsigned short* __restrict__ O, int b, int hh, int qw0,
                    int lane, int lo, int hi) {
  const float inv = 1.f / lrun;
#pragma unroll
  for (int et = 0; et < 4; ++et) {
    f32x4 o = oacc[et] * inv;
    u32x2 d = {cvtpk(o[0], o[1]), cvtpk(o[2], o[3])};
    *(u32x2*)&pbw[lo * 72 + et * 16 + hi * 4] = d;
  }
  int q = lane >> 2, seg = lane & 3;
  unsigned short* dst = O + ((size_t)b * Sseq + qw0 + q) * Dm + hh * HSn + seg * 16;
  *(s16x8*)dst = *(const s16x8*)&pbw[q * 72 + seg * 16];
  *(s16x8*)(dst + 8) = *(const s16x8*)&pbw[q * 72 + seg * 16 + 8];
}

__global__ __launch_bounds__(512, 4) void attn_kernel(const unsigned short* __restrict__ Q,
                                                      const unsigned short* __restrict__ Kg,
                                                      const unsigned short* __restrict__ Vt,
                                                      unsigned short* __restrict__ O,
                                                      const int* __restrict__ pad,
                                                      const int* __restrict__ tmask,
                                                      const int* __restrict__ flags) {
  __shared__ unsigned short kb[2][64 * 72];     // 18 KiB
  __shared__ unsigned short vb[2][64 * 72];     // 18 KiB
  __shared__ unsigned short pb[8][2][16 * 72];  // 36 KiB (per-wave, per-column)

  const int ip = blockIdx.x, bh = blockIdx.y;
  const int b = bh >> 4, hh = bh & 15;
  const int tid = threadIdx.x, w = tid >> 6, lane = tid & 63, lo = lane & 15, hi = lane >> 4;
  const int qtA = ip, qtB = 15 - ip;
  const int qw0A = qtA * 128 + w * 16, qw0B = qtB * 128 + w * 16;
  const int ktmax = 2 * qtB + 2;
  const bool trivial = flags[0] == 0;

  const unsigned short* Qb = Q + (size_t)bh * Sseq * HSn;
  const unsigned short* Kb = Kg + (size_t)bh * Sseq * HSn;
  const unsigned short* Vb = Vt + (size_t)bh * HSn * Sseq;

  s16x8 qfA[2], qfB[2];
#pragma unroll
  for (int kk = 0; kk < 2; ++kk) {
    qfA[kk] = *(const s16x8*)&Qb[(size_t)(qw0A + lo) * HSn + kk * 32 + hi * 8];
    qfB[kk] = *(const s16x8*)&Qb[(size_t)(qw0B + lo) * HSn + kk * 32 + hi * 8];
  }

  s16x8 ones;
#pragma unroll
  for (int j = 0; j < 8; ++j) ones[j] = (short)0x3F80; // bf16 1.0

  f32x4 oaccA[4] = {}, oaccB[4] = {};
  f32x4 laccA = {}, laccB = {};
  float mrunA = -3e38f, mrunB = -3e38f;

  // staging: waves 0-3 handle K, waves 4-7 handle V
  const int shalf = tid >> 8, st_t = tid & 255;
  const int sr = st_t >> 2, sc = (st_t & 3) * 16;

  s16x8 r0, r1;
  if (shalf == 0) {
    const unsigned short* gk = Kb + (size_t)sr * HSn + sc;
    r0 = *(const s16x8*)gk; r1 = *(const s16x8*)(gk + 8);
    *(s16x8*)&kb[0][sr * 72 + sc] = r0; *(s16x8*)&kb[0][sr * 72 + sc + 8] = r1;
  } else {
    const unsigned short* gv = Vb + (size_t)sr * Sseq + sc;
    r0 = *(const s16x8*)gv; r1 = *(const s16x8*)(gv + 8);
    *(s16x8*)&vb[0][sr * 72 + sc] = r0; *(s16x8*)&vb[0][sr * 72 + sc + 8] = r1;
  }
  __syncthreads();

  for (int kt = 0; kt < ktmax; ++kt) {
    const int cur = kt & 1, k0 = kt * 64;
    const bool pre = (kt + 1 < ktmax);
    if (pre) { // issue next-tile loads early
      const int k1 = k0 + 64;
      if (shalf == 0) {
        const unsigned short* gk = Kb + (size_t)(k1 + sr) * HSn + sc;
        r0 = *(const s16x8*)gk; r1 = *(const s16x8*)(gk + 8);
      } else {
        const unsigned short* gv = Vb + (size_t)sr * Sseq + k1 + sc;
        r0 = *(const s16x8*)gv; r1 = *(const s16x8*)(gv + 8);
      }
    }
    const unsigned short* kbc = kb[cur];
    const unsigned short* vbc = vb[cur];
    const bool actB = (k0 <= qw0B + 15);       // wave-uniform
    if (actB) {
      const bool actA = (k0 <= qw0A + 15);     // actA implies actB (qw0A < qw0B)
      // QK^T for both columns, sharing each kfr read
      f32x4 stA[4], stB[4];
#pragma unroll
      for (int t = 0; t < 4; ++t) {
        f32x4 zA = {0.f, 0.f, 0.f, 0.f}, zB = {0.f, 0.f, 0.f, 0.f};
#pragma unroll
        for (int kk = 0; kk < 2; ++kk) {
          s16x8 kfr = *(const s16x8*)&kbc[(t * 16 + lo) * 72 + kk * 32 + hi * 8];
          if (actA) zA = __builtin_amdgcn_mfma_f32_16x16x32_bf16(kfr, qfA[kk], zA, 0, 0, 0);
          zB = __builtin_amdgcn_mfma_f32_16x16x32_bf16(kfr, qfB[kk], zB, 0, 0, 0);
        }
        stA[t] = zA; stB[t] = zB;
      }
      if (actA)
        softmax_col(stA, k0, qw0A, lo, hi, b, pad, tmask, trivial, mrunA, oaccA, laccA, pb[w][0]);
      softmax_col(stB, k0, qw0B, lo, hi, b, pad, tmask, trivial, mrunB, oaccB, laccB, pb[w][1]);
      // PV for both columns, sharing each vfr read
      s16x8 pfA[2], pfB[2];
#pragma unroll
      for (int kk = 0; kk < 2; ++kk) {
        if (actA) pfA[kk] = *(const s16x8*)&pb[w][0][lo * 72 + kk * 32 + hi * 8];
        pfB[kk] = *(const s16x8*)&pb[w][1][lo * 72 + kk * 32 + hi * 8];
      }
#pragma unroll
      for (int et = 0; et < 4; ++et)
#pragma unroll
        for (int kk = 0; kk < 2; ++kk) {
          s16x8 vfr = *(const s16x8*)&vbc[(et * 16 + lo) * 72 + kk * 32 + hi * 8];
          if (actA) oaccA[et] = __builtin_amdgcn_mfma_f32_16x16x32_bf16(vfr, pfA[kk], oaccA[et], 0, 0, 0);
          oaccB[et] = __builtin_amdgcn_mfma_f32_16x16x32_bf16(vfr, pfB[kk], oaccB[et], 0, 0, 0);
        }
      if (actA) {
        laccA = __builtin_amdgcn_mfma_f32_16x16x32_bf16(ones, pfA[0], laccA, 0, 0, 0);
        laccA = __builtin_amdgcn_mfma_f32_16x16x32_bf16(ones, pfA[1], laccA, 0, 0, 0);
      }
      laccB = __builtin_amdgcn_mfma_f32_16x16x32_bf16(ones, pfB[0], laccB, 0, 0, 0);
      laccB = __builtin_amdgcn_mfma_f32_16x16x32_bf16(ones, pfB[1], laccB, 0, 0, 0);
    }
    if (pre) { // write-late into the other buffer
      const int nb = cur ^ 1;
      if (shalf == 0) {
        *(s16x8*)&kb[nb][sr * 72 + sc] = r0; *(s16x8*)&kb[nb][sr * 72 + sc + 8] = r1;
      } else {
        *(s16x8*)&vb[nb][sr * 72 + sc] = r0; *(s16x8*)&vb[nb][sr * 72 + sc + 8] = r1;
      }
    }
    __syncthreads();
  }

  attn_epi16(oaccA, laccA[0], pb[w][0], O, b, hh, qw0A, lane, lo, hi);
  attn_epi16(oaccB, laccB[0], pb[w][1], O, b, hh, qw0B, lane, lo, hi);
}

extern "C" void kernel_launch(void* const* d_in, const int* in_sizes, int n_in,
                              void* d_out, int out_size, void* d_ws, size_t ws_size,
                              hipStream_t stream) {
  const float* x = (const float*)d_in[0];
  const float* y = (const float*)d_in[1];
  const int* pad = (const int*)d_in[2];
  const int* tmask = (const int*)d_in[3];
  const float* Wq = (const float*)d_in[4];
  const float* Wk = (const float*)d_in[5];
  const float* Wv = (const float*)d_in[6];
  const float* Wp = (const float*)d_in[7];
  const float* bp = (const float*)d_in[8];

  char* ws = (char*)d_ws;
  unsigned short* xbf = (unsigned short*)(ws + OFF_XBF);
  unsigned short* ybf = (unsigned short*)(ws + OFF_YBF);
  unsigned short* wqb = (unsigned short*)(ws + OFF_WQ);
  unsigned short* wkb = (unsigned short*)(ws + OFF_WK);
  unsigned short* wvb = (unsigned short*)(ws + OFF_WV);
  unsigned short* wpb = (unsigned short*)(ws + OFF_WP);
  unsigned short* qws = (unsigned short*)(ws + OFF_QWS);
  unsigned short* kws = (unsigned short*)(ws + OFF_KWS);
  unsigned short* vtw = (unsigned short*)(ws + OFF_VTWS);
  unsigned short* ows = (unsigned short*)(ws + OFF_OWS);
  int* flags = (int*)(ws + OFF_FLAG);

  hipMemsetAsync(flags, 0, 4, stream);
  cvt_all<<<12296, 256, 0, stream>>>(x, y, Wq, Wk, Wv, Wp, pad, tmask, ws, flags);

  q_gemm<<<dim3(64, 8), 256, 0, stream>>>(ybf, wqb, qws);
  kv_gemm<<<dim3(64, 8), 256, 0, stream>>>(xbf, wkb, wvb, kws, vtw);

  attn_kernel<<<dim3(8, 64), 512, 0, stream>>>(qws, kws, vtw, ows, pad, tmask, flags);

  gemm_p<<<dim3(64, 8), 256, 0, stream>>>(ows, wpb, (float*)d_out, bp);
}

// Round 12
// 190.835 us; speedup vs baseline: 1.1148x; 1.1148x over previous
//
#include <hip/hip_runtime.h>
#include <hip/hip_bf16.h>
#include <stdint.h>
#include <stddef.h>

// MultiHA: y@Wq^T -> q; x@Wk^T -> k; x@Wv^T -> v; causal softmax attn; @Wp^T + bp
// B=4 S=2048 D=1024 NH=16 HS=64. All GEMM/attn compute in bf16 MFMA, f32 accum.

typedef __attribute__((ext_vector_type(4))) float f32x4;
typedef __attribute__((ext_vector_type(8))) short s16x8;
typedef __attribute__((ext_vector_type(4))) float float4v;
typedef __attribute__((ext_vector_type(4))) int i32x4;
typedef __attribute__((ext_vector_type(2))) unsigned int u32x2;

#define DEV __device__ __forceinline__

constexpr int Bsz = 4, Sseq = 2048, Dm = 1024, NHn = 16, HSn = 64;
// fold 1/sqrt(HS) * log2(e) into Wq so attention softmax runs in exp2 domain
constexpr float QSCALE = 0.125f * 1.4426950408889634f;

// ---- workspace layout (bytes) ----
constexpr size_t SZ_BF_XY = (size_t)Bsz * Sseq * Dm * 2;  // 16 MiB
constexpr size_t SZ_W     = (size_t)Dm * Dm * 2;          // 2 MiB
constexpr size_t OFF_XBF  = 0;
constexpr size_t OFF_YBF  = OFF_XBF + SZ_BF_XY;
constexpr size_t OFF_WQ   = OFF_YBF + SZ_BF_XY;
constexpr size_t OFF_WK   = OFF_WQ + SZ_W;
constexpr size_t OFF_WV   = OFF_WK + SZ_W;
constexpr size_t OFF_WP   = OFF_WV + SZ_W;
constexpr size_t OFF_QWS  = OFF_WP + SZ_W;   // [BH][S][64] bf16
constexpr size_t OFF_KWS  = OFF_QWS + SZ_BF_XY;
constexpr size_t OFF_VTWS = OFF_KWS + SZ_BF_XY; // [BH][64][S] bf16 (V transposed)
constexpr size_t OFF_OWS  = OFF_VTWS + SZ_BF_XY; // attn out [B][S][D] bf16
constexpr size_t OFF_FLAG = OFF_OWS + SZ_BF_XY;

DEV unsigned short f2bf(float f) {
  union { float f; unsigned int u; } v; v.f = f;
  unsigned int r = (v.u + 0x7FFFu + ((v.u >> 16) & 1u)) >> 16;
  return (unsigned short)r;
}

DEV void gll16(const void* g, void* l) {
  __builtin_amdgcn_global_load_lds((const __attribute__((address_space(1))) unsigned int*)g,
                                   (__attribute__((address_space(3))) unsigned int*)l, 16, 0, 0);
}

DEV unsigned int cvtpk(float a, float b) {
  unsigned int r;
  asm("v_cvt_pk_bf16_f32 %0, %1, %2" : "=v"(r) : "v"(a), "v"(b));
  return r;
}

// ------ fused fp32->bf16 conversion of all inputs + pad/tmask triviality check ------
__global__ void cvt_all(const float* __restrict__ x, const float* __restrict__ y,
                        const float* __restrict__ Wq, const float* __restrict__ Wk,
                        const float* __restrict__ Wv, const float* __restrict__ Wp,
                        const int* __restrict__ pad, const int* __restrict__ tmask,
                        char* __restrict__ ws, int* __restrict__ flags) {
  const int blk = blockIdx.x;
  if (blk >= 10240) {
    int bad = 0;
    if (blk < 10248) { // pad: 8192 ints, 4 per thread
      const i32x4 v = ((const i32x4*)pad)[(blk - 10240) * 256 + threadIdx.x];
      bad = (v[0] == 0) | (v[1] == 0) | (v[2] == 0) | (v[3] == 0);
    } else { // tmask: 4M ints, 8 per thread
      const i32x4* tp = (const i32x4*)tmask + ((size_t)(blk - 10248) * 256 + threadIdx.x) * 2;
      i32x4 v0 = tp[0], v1 = tp[1];
      bad = (v0[0] == 0) | (v0[1] == 0) | (v0[2] == 0) | (v0[3] == 0) |
            (v1[0] == 0) | (v1[1] == 0) | (v1[2] == 0) | (v1[3] == 0);
    }
    if (__builtin_amdgcn_ballot_w64(bad) != 0 && (threadIdx.x & 63) == 0)
      atomicOr(flags, 1);
    return;
  }
  const float* src;
  unsigned short* dst;
  int b8;
  float scale = 1.f;
  if (blk < 4096)      { src = x;  dst = (unsigned short*)(ws + OFF_XBF); b8 = blk; }
  else if (blk < 8192) { src = y;  dst = (unsigned short*)(ws + OFF_YBF); b8 = blk - 4096; }
  else if (blk < 8704) { src = Wq; dst = (unsigned short*)(ws + OFF_WQ);  b8 = blk - 8192; scale = QSCALE; }
  else if (blk < 9216) { src = Wk; dst = (unsigned short*)(ws + OFF_WK);  b8 = blk - 8704; }
  else if (blk < 9728) { src = Wv; dst = (unsigned short*)(ws + OFF_WV);  b8 = blk - 9216; }
  else                 { src = Wp; dst = (unsigned short*)(ws + OFF_WP);  b8 = blk - 9728; }
  const size_t i = (size_t)b8 * 256 + threadIdx.x;
  const float4v* s = (const float4v*)src + i * 2;
  float4v a = s[0], b = s[1];
  s16x8 o;
  o[0] = (short)f2bf(a[0] * scale); o[1] = (short)f2bf(a[1] * scale);
  o[2] = (short)f2bf(a[2] * scale); o[3] = (short)f2bf(a[3] * scale);
  o[4] = (short)f2bf(b[0] * scale); o[5] = (short)f2bf(b[1] * scale);
  o[6] = (short)f2bf(b[2] * scale); o[7] = (short)f2bf(b[3] * scale);
  *(s16x8*)(dst + i * 8) = o;
}

// ---------------- Q projection GEMM (2-phase double-buffered staging) ----------------
__global__ __launch_bounds__(256) void q_gemm(const unsigned short* __restrict__ A,
                                              const unsigned short* __restrict__ W,
                                              unsigned short* __restrict__ outb) {
  constexpr int K = 1024;
  __shared__ unsigned short sm[2][8192]; // [buf][lA 4096 | lB 4096]
  const int tid = threadIdx.x;
  const int w = tid >> 6, lane = tid & 63, lo = lane & 15, hi = lane >> 4;
  const int wm = w >> 1, wn = w & 1;
  const int m0 = blockIdx.x * 128, n0 = blockIdx.y * 128;
  f32x4 acc[4][4] = {};

  auto stage = [&](int buf, int k0) {
#pragma unroll
    for (int h = 0; h < 2; ++h) {
      int c = w * 64 + h * 256 + lane;
      gll16(A + (size_t)(m0 + (c >> 2)) * K + k0 + (c & 3) * 8, &sm[buf][0] + (size_t)(w * 64 + h * 256) * 8);
      gll16(W + (size_t)(n0 + (c >> 2)) * K + k0 + (c & 3) * 8, &sm[buf][4096] + (size_t)(w * 64 + h * 256) * 8);
    }
  };

  stage(0, 0);
  __syncthreads(); // drains vmcnt -> buf0 ready
  for (int t = 0; t < 32; ++t) {
    if (t < 31) stage((t + 1) & 1, (t + 1) * 32); // issue next tile early
    const unsigned short* lA = &sm[t & 1][0];
    const unsigned short* lB = &sm[t & 1][4096];
    s16x8 af[4], bfr[4];
#pragma unroll
    for (int mi = 0; mi < 4; ++mi) af[mi] = *(const s16x8*)&lA[(wm * 64 + mi * 16 + lo) * 32 + hi * 8];
#pragma unroll
    for (int ni = 0; ni < 4; ++ni) bfr[ni] = *(const s16x8*)&lB[(wn * 64 + ni * 16 + lo) * 32 + hi * 8];
#pragma unroll
    for (int mi = 0; mi < 4; ++mi)
#pragma unroll
      for (int ni = 0; ni < 4; ++ni)
        acc[mi][ni] = __builtin_amdgcn_mfma_f32_16x16x32_bf16(af[mi], bfr[ni], acc[mi][ni], 0, 0, 0);
    __syncthreads(); // readers done + next-tile loads drained
  }
#pragma unroll
  for (int mi = 0; mi < 4; ++mi)
#pragma unroll
    for (int ni = 0; ni < 4; ++ni)
#pragma unroll
      for (int j = 0; j < 4; ++j) {
        int m = m0 + wm * 64 + mi * 16 + hi * 4 + j;
        int n = n0 + wn * 64 + ni * 16 + lo;
        int b = m >> 11, s = m & 2047, hh = n >> 6, e = n & 63;
        outb[((size_t)(b * NHn + hh) * Sseq + s) * HSn + e] = f2bf(acc[mi][ni][j]);
      }
}

// -------- merged K+V projection GEMM (shared x staging, 2-phase double-buffer) --------
__global__ __launch_bounds__(256, 2) void kv_gemm(const unsigned short* __restrict__ A,
                                                  const unsigned short* __restrict__ Wk,
                                                  const unsigned short* __restrict__ Wv,
                                                  unsigned short* __restrict__ kws,
                                                  unsigned short* __restrict__ vtw) {
  constexpr int K = 1024;
  __shared__ unsigned short sm[2][12288]; // [buf][lA | lBk | lBv]; epilogue reuses flat
  const int tid = threadIdx.x;
  const int w = tid >> 6, lane = tid & 63, lo = lane & 15, hi = lane >> 4;
  const int wm = w >> 1, wn = w & 1;
  const int m0 = blockIdx.x * 128, n0 = blockIdx.y * 128;
  f32x4 acck[4][4] = {}, accv[4][4] = {};

  auto stage = [&](int buf, int k0) {
#pragma unroll
    for (int h = 0; h < 2; ++h) {
      int c = w * 64 + h * 256 + lane;
      size_t roff = (size_t)(c >> 2) * K + k0 + (c & 3) * 8;
      size_t loff = (size_t)(w * 64 + h * 256) * 8;
      gll16(A + (size_t)m0 * K + roff, &sm[buf][0] + loff);
      gll16(Wk + (size_t)n0 * K + roff, &sm[buf][4096] + loff);
      gll16(Wv + (size_t)n0 * K + roff, &sm[buf][8192] + loff);
    }
  };

  stage(0, 0);
  __syncthreads();
  for (int t = 0; t < 32; ++t) {
    if (t < 31) stage((t + 1) & 1, (t + 1) * 32);
    const unsigned short* lA = &sm[t & 1][0];
    const unsigned short* lBk = &sm[t & 1][4096];
    const unsigned short* lBv = &sm[t & 1][8192];
    s16x8 af[4], bfk[4], bfv[4];
#pragma unroll
    for (int mi = 0; mi < 4; ++mi) af[mi] = *(const s16x8*)&lA[(wm * 64 + mi * 16 + lo) * 32 + hi * 8];
#pragma unroll
    for (int ni = 0; ni < 4; ++ni) {
      bfk[ni] = *(const s16x8*)&lBk[(wn * 64 + ni * 16 + lo) * 32 + hi * 8];
      bfv[ni] = *(const s16x8*)&lBv[(wn * 64 + ni * 16 + lo) * 32 + hi * 8];
    }
#pragma unroll
    for (int mi = 0; mi < 4; ++mi)
#pragma unroll
      for (int ni = 0; ni < 4; ++ni) {
        acck[mi][ni] = __builtin_amdgcn_mfma_f32_16x16x32_bf16(af[mi], bfk[ni], acck[mi][ni], 0, 0, 0);
        accv[mi][ni] = __builtin_amdgcn_mfma_f32_16x16x32_bf16(af[mi], bfv[ni], accv[mi][ni], 0, 0, 0);
      }
    __syncthreads();
  }

  // K epilogue: direct global stores
#pragma unroll
  for (int mi = 0; mi < 4; ++mi)
#pragma unroll
    for (int ni = 0; ni < 4; ++ni)
#pragma unroll
      for (int j = 0; j < 4; ++j) {
        int m = m0 + wm * 64 + mi * 16 + hi * 4 + j;
        int n = n0 + wn * 64 + ni * 16 + lo;
        int b = m >> 11, s = m & 2047, hh = n >> 6, e = n & 63;
        kws[((size_t)(b * NHn + hh) * Sseq + s) * HSn + e] = f2bf(acck[mi][ni][j]);
      }
  // V epilogue: LDS transpose (reuses sm flat: needs 17408 shorts < 24576)
  unsigned short* tp = &sm[0][0];
  __syncthreads();
#pragma unroll
  for (int mi = 0; mi < 4; ++mi)
#pragma unroll
    for (int ni = 0; ni < 4; ++ni)
#pragma unroll
      for (int j = 0; j < 4; ++j) {
        int ml = wm * 64 + mi * 16 + hi * 4 + j;
        int nl = wn * 64 + ni * 16 + lo;
        tp[(size_t)nl * 136 + ml] = f2bf(accv[mi][ni][j]);
      }
  __syncthreads();
  int nl = tid >> 1, half = tid & 1;
  int b = m0 >> 11, hh = (n0 + nl) >> 6, e = (n0 + nl) & 63;
  unsigned short* dst = vtw + ((size_t)(b * NHn + hh) * HSn + e) * Sseq + (m0 & 2047) + half * 64;
#pragma unroll
  for (int i = 0; i < 8; ++i)
    *(s16x8*)(dst + i * 8) = *(const s16x8*)&tp[(size_t)nl * 136 + half * 64 + i * 8];
}

// ---------------- final projection GEMM (2-phase): fp32 out [M][1024] + bias ----------
__global__ __launch_bounds__(256) void gemm_p(const unsigned short* __restrict__ A,
                                              const unsigned short* __restrict__ W,
                                              float* __restrict__ outf,
                                              const float* __restrict__ bias) {
  constexpr int K = 1024;
  __shared__ unsigned short sm[2][8192];
  const int tid = threadIdx.x;
  const int w = tid >> 6, lane = tid & 63, lo = lane & 15, hi = lane >> 4;
  const int wm = w >> 1, wn = w & 1;
  const int m0 = blockIdx.x * 128, n0 = blockIdx.y * 128;
  f32x4 acc[4][4] = {};

  auto stage = [&](int buf, int k0) {
#pragma unroll
    for (int h = 0; h < 2; ++h) {
      int c = w * 64 + h * 256 + lane;
      gll16(A + (size_t)(m0 + (c >> 2)) * K + k0 + (c & 3) * 8, &sm[buf][0] + (size_t)(w * 64 + h * 256) * 8);
      gll16(W + (size_t)(n0 + (c >> 2)) * K + k0 + (c & 3) * 8, &sm[buf][4096] + (size_t)(w * 64 + h * 256) * 8);
    }
  };

  stage(0, 0);
  __syncthreads();
  for (int t = 0; t < 32; ++t) {
    if (t < 31) stage((t + 1) & 1, (t + 1) * 32);
    const unsigned short* lA = &sm[t & 1][0];
    const unsigned short* lB = &sm[t & 1][4096];
    s16x8 af[4], bfr[4];
#pragma unroll
    for (int mi = 0; mi < 4; ++mi) af[mi] = *(const s16x8*)&lA[(wm * 64 + mi * 16 + lo) * 32 + hi * 8];
#pragma unroll
    for (int ni = 0; ni < 4; ++ni) bfr[ni] = *(const s16x8*)&lB[(wn * 64 + ni * 16 + lo) * 32 + hi * 8];
#pragma unroll
    for (int mi = 0; mi < 4; ++mi)
#pragma unroll
      for (int ni = 0; ni < 4; ++ni)
        acc[mi][ni] = __builtin_amdgcn_mfma_f32_16x16x32_bf16(af[mi], bfr[ni], acc[mi][ni], 0, 0, 0);
    __syncthreads();
  }
  float bv[4];
#pragma unroll
  for (int ni = 0; ni < 4; ++ni) bv[ni] = bias[n0 + wn * 64 + ni * 16 + lo];
#pragma unroll
  for (int mi = 0; mi < 4; ++mi)
#pragma unroll
    for (int ni = 0; ni < 4; ++ni)
#pragma unroll
      for (int j = 0; j < 4; ++j) {
        int m = m0 + wm * 64 + mi * 16 + hi * 4 + j;
        int n = n0 + wn * 64 + ni * 16 + lo;
        outf[(size_t)m * 1024 + n] = acc[mi][ni][j] + bv[ni];
      }
}

// ---------------- flash attention (8-wave blocks, 16 rows/wave, swapped-QK^T) ----------
// R9-verified kernel; R12 change: grid swapped to (bh, ip) so the 8 ip-blocks sharing
// one head's K/V have linear IDs differing by 64 (== 0 mod 8) -> same XCD -> K/V
// becomes L2-resident instead of 8x HBM refetch.
// st[t][j] = S[kpos=k0+t*16+hi*4+j][q=qw0+lo]; oacc[et][j] = O^T[e=et*16+hi*4+j][q].
// Defer-max (thr=11 in exp2 domain) + l via ones-MFMA.
DEV void attn_unit16(const unsigned short* __restrict__ kbc,
                     const unsigned short* __restrict__ vbc,
                     const s16x8 (&qf)[2], f32x4 (&oacc)[4], f32x4& lacc,
                     float& mrun, const s16x8& ones,
                     unsigned short* __restrict__ pbw,
                     int k0, int qw0, int lo, int hi, int b,
                     const int* __restrict__ pad, const int* __restrict__ tmask,
                     bool trivial) {
  if (k0 > qw0 + 15) return; // wave-uniform: tile entirely above this wave's rows

  // S^T = K Q^T (operand-swapped)
  f32x4 st[4];
#pragma unroll
  for (int t = 0; t < 4; ++t) {
    f32x4 z = {0.f, 0.f, 0.f, 0.f};
#pragma unroll
    for (int kk = 0; kk < 2; ++kk) {
      s16x8 kfr = *(const s16x8*)&kbc[(t * 16 + lo) * 72 + kk * 32 + hi * 8];
      z = __builtin_amdgcn_mfma_f32_16x16x32_bf16(kfr, qf[kk], z, 0, 0, 0);
    }
    st[t] = z;
  }
  const int qg = qw0 + lo;
  if (k0 + 63 > qw0) { // diagonal tiles: causal mask (kpos > q)
#pragma unroll
    for (int t = 0; t < 4; ++t)
#pragma unroll
      for (int j = 0; j < 4; ++j)
        if (k0 + t * 16 + hi * 4 + j > qg) st[t][j] = -3e38f;
  }
  if (!trivial) { // general pad/time masks (not hit for all-ones inputs)
#pragma unroll
    for (int t = 0; t < 4; ++t)
#pragma unroll
      for (int j = 0; j < 4; ++j) {
        int kg = k0 + t * 16 + hi * 4 + j;
        if (!pad[b * Sseq + kg] || !tmask[(size_t)qg * Sseq + kg]) st[t][j] = -3e38f;
      }
  }
  // tile max for this lane's q-column (lane-local + 2 shuffles over hi-groups)
  float m0v = fmaxf(fmaxf(st[0][0], st[0][1]), fmaxf(st[0][2], st[0][3]));
  float m1v = fmaxf(fmaxf(st[1][0], st[1][1]), fmaxf(st[1][2], st[1][3]));
  float m2v = fmaxf(fmaxf(st[2][0], st[2][1]), fmaxf(st[2][2], st[2][3]));
  float m3v = fmaxf(fmaxf(st[3][0], st[3][1]), fmaxf(st[3][2], st[3][3]));
  float mx = fmaxf(fmaxf(m0v, m1v), fmaxf(m2v, m3v));
  mx = fmaxf(mx, __shfl_xor(mx, 16, 64));
  mx = fmaxf(mx, __shfl_xor(mx, 32, 64));
  // defer-max: only rescale when the bound would be exceeded (P <= 2^11 otherwise)
  if (!__all(mx <= mrun + 11.f)) {
    const float mnew = fmaxf(mrun, mx);
    const float al = __builtin_amdgcn_exp2f(mrun - mnew);
    mrun = mnew;
#pragma unroll
    for (int et = 0; et < 4; ++et) oacc[et] *= al;
    lacc *= al;
  }
  // P = exp2(S - mrun)
#pragma unroll
  for (int t = 0; t < 4; ++t)
#pragma unroll
    for (int j = 0; j < 4; ++j)
      st[t][j] = __builtin_amdgcn_exp2f(st[t][j] - mrun);
  // pack P column segment -> pb[q][kpos] (b64 writes, 4 kpos each)
#pragma unroll
  for (int t = 0; t < 4; ++t) {
    u32x2 dd = {cvtpk(st[t][0], st[t][1]), cvtpk(st[t][2], st[t][3])};
    *(u32x2*)&pbw[lo * 72 + t * 16 + hi * 4] = dd;
  }
  // O^T += V^T P^T ; l += ones . P (extra MFMA pair, all rows equal l[q])
  s16x8 pf[2];
#pragma unroll
  for (int kk = 0; kk < 2; ++kk)
    pf[kk] = *(const s16x8*)&pbw[lo * 72 + kk * 32 + hi * 8];
#pragma unroll
  for (int et = 0; et < 4; ++et)
#pragma unroll
    for (int kk = 0; kk < 2; ++kk) {
      s16x8 vfr = *(const s16x8*)&vbc[(et * 16 + lo) * 72 + kk * 32 + hi * 8];
      oacc[et] = __builtin_amdgcn_mfma_f32_16x16x32_bf16(vfr, pf[kk], oacc[et], 0, 0, 0);
    }
  lacc = __builtin_amdgcn_mfma_f32_16x16x32_bf16(ones, pf[0], lacc, 0, 0, 0);
  lacc = __builtin_amdgcn_mfma_f32_16x16x32_bf16(ones, pf[1], lacc, 0, 0, 0);
}

// normalize by l (lane-local) and write O via per-wave LDS transpose (16 rows)
DEV void attn_epi16(f32x4 (&oacc)[4], float lrun,
                    unsigned short* __restrict__ pbw,
                    unsigned short* __restrict__ O, int b, int hh, int qw0,
                    int lane, int lo, int hi) {
  const float inv = 1.f / lrun;
#pragma unroll
  for (int et = 0; et < 4; ++et) {
    f32x4 o = oacc[et] * inv;
    u32x2 d = {cvtpk(o[0], o[1]), cvtpk(o[2], o[3])};
    *(u32x2*)&pbw[lo * 72 + et * 16 + hi * 4] = d;
  }
  int q = lane >> 2, seg = lane & 3;
  unsigned short* dst = O + ((size_t)b * Sseq + qw0 + q) * Dm + hh * HSn + seg * 16;
  *(s16x8*)dst = *(const s16x8*)&pbw[q * 72 + seg * 16];
  *(s16x8*)(dst + 8) = *(const s16x8*)&pbw[q * 72 + seg * 16 + 8];
}

__global__ __launch_bounds__(512, 4) void attn_kernel(const unsigned short* __restrict__ Q,
                                                      const unsigned short* __restrict__ Kg,
                                                      const unsigned short* __restrict__ Vt,
                                                      unsigned short* __restrict__ O,
                                                      const int* __restrict__ pad,
                                                      const int* __restrict__ tmask,
                                                      const int* __restrict__ flags) {
  __shared__ unsigned short kb[2][64 * 72];   // 18.0 KiB
  __shared__ unsigned short vb[2][64 * 72];   // 18.0 KiB
  __shared__ unsigned short pb[8][16 * 72];   // 18.0 KiB (wave-private P scratch)

  const int ip = blockIdx.y, bh = blockIdx.x; // R12: bh fastest -> same-bh blocks on one XCD
  const int b = bh >> 4, hh = bh & 15;
  const int tid = threadIdx.x, w = tid >> 6, lane = tid & 63, lo = lane & 15, hi = lane >> 4;
  const int qtA = ip, qtB = 15 - ip;
  const int qw0A = qtA * 128 + w * 16, qw0B = qtB * 128 + w * 16;
  const int ktA = 2 * qtA + 1;       // last K-tile index tile A needs (any wave)
  const int ktmax = 2 * qtB + 2;     // number of K-tiles tile B needs
  const bool trivial = flags[0] == 0;

  const unsigned short* Qb = Q + (size_t)bh * Sseq * HSn;
  const unsigned short* Kb = Kg + (size_t)bh * Sseq * HSn;
  const unsigned short* Vb = Vt + (size_t)bh * HSn * Sseq;

  // Q fragments (B-operand of swapped QK^T)
  s16x8 qfA[2], qfB[2];
#pragma unroll
  for (int kk = 0; kk < 2; ++kk) {
    qfA[kk] = *(const s16x8*)&Qb[(size_t)(qw0A + lo) * HSn + kk * 32 + hi * 8];
    qfB[kk] = *(const s16x8*)&Qb[(size_t)(qw0B + lo) * HSn + kk * 32 + hi * 8];
  }

  s16x8 ones;
#pragma unroll
  for (int j = 0; j < 8; ++j) ones[j] = (short)0x3F80; // bf16 1.0

  f32x4 oaccA[4] = {}, oaccB[4] = {};
  f32x4 laccA = {}, laccB = {};
  float mrunA = -3e38f, mrunB = -3e38f;

  // staging: waves 0-3 handle K, waves 4-7 handle V (256 threads each)
  const int shalf = tid >> 8, st_t = tid & 255;
  const int sr = st_t >> 2, sc = (st_t & 3) * 16;

  // prologue: stage kt=0 into buffer 0
  s16x8 r0, r1;
  if (shalf == 0) {
    const unsigned short* gk = Kb + (size_t)sr * HSn + sc;
    r0 = *(const s16x8*)gk; r1 = *(const s16x8*)(gk + 8);
    *(s16x8*)&kb[0][sr * 72 + sc] = r0; *(s16x8*)&kb[0][sr * 72 + sc + 8] = r1;
  } else {
    const unsigned short* gv = Vb + (size_t)sr * Sseq + sc;
    r0 = *(const s16x8*)gv; r1 = *(const s16x8*)(gv + 8);
    *(s16x8*)&vb[0][sr * 72 + sc] = r0; *(s16x8*)&vb[0][sr * 72 + sc + 8] = r1;
  }
  __syncthreads();

  for (int kt = 0; kt < ktmax; ++kt) {
    const int cur = kt & 1, k0 = kt * 64;
    const bool pre = (kt + 1 < ktmax);
    if (pre) { // issue next-tile loads early; latency hides under compute
      const int k1 = k0 + 64;
      if (shalf == 0) {
        const unsigned short* gk = Kb + (size_t)(k1 + sr) * HSn + sc;
        r0 = *(const s16x8*)gk; r1 = *(const s16x8*)(gk + 8);
      } else {
        const unsigned short* gv = Vb + (size_t)sr * Sseq + k1 + sc;
        r0 = *(const s16x8*)gv; r1 = *(const s16x8*)(gv + 8);
      }
    }
    const unsigned short* kbc = kb[cur];
    const unsigned short* vbc = vb[cur];
    if (kt <= ktA)
      attn_unit16(kbc, vbc, qfA, oaccA, laccA, mrunA, ones, pb[w],
                  k0, qw0A, lo, hi, b, pad, tmask, trivial);
    attn_unit16(kbc, vbc, qfB, oaccB, laccB, mrunB, ones, pb[w],
                k0, qw0B, lo, hi, b, pad, tmask, trivial);
    if (pre) { // write-late into the other buffer
      const int nb = cur ^ 1;
      if (shalf == 0) {
        *(s16x8*)&kb[nb][sr * 72 + sc] = r0; *(s16x8*)&kb[nb][sr * 72 + sc + 8] = r1;
      } else {
        *(s16x8*)&vb[nb][sr * 72 + sc] = r0; *(s16x8*)&vb[nb][sr * 72 + sc + 8] = r1;
      }
    }
    __syncthreads();
  }

  attn_epi16(oaccA, laccA[0], pb[w], O, b, hh, qw0A, lane, lo, hi);
  attn_epi16(oaccB, laccB[0], pb[w], O, b, hh, qw0B, lane, lo, hi);
}

extern "C" void kernel_launch(void* const* d_in, const int* in_sizes, int n_in,
                              void* d_out, int out_size, void* d_ws, size_t ws_size,
                              hipStream_t stream) {
  const float* x = (const float*)d_in[0];
  const float* y = (const float*)d_in[1];
  const int* pad = (const int*)d_in[2];
  const int* tmask = (const int*)d_in[3];
  const float* Wq = (const float*)d_in[4];
  const float* Wk = (const float*)d_in[5];
  const float* Wv = (const float*)d_in[6];
  const float* Wp = (const float*)d_in[7];
  const float* bp = (const float*)d_in[8];

  char* ws = (char*)d_ws;
  unsigned short* xbf = (unsigned short*)(ws + OFF_XBF);
  unsigned short* ybf = (unsigned short*)(ws + OFF_YBF);
  unsigned short* wqb = (unsigned short*)(ws + OFF_WQ);
  unsigned short* wkb = (unsigned short*)(ws + OFF_WK);
  unsigned short* wvb = (unsigned short*)(ws + OFF_WV);
  unsigned short* wpb = (unsigned short*)(ws + OFF_WP);
  unsigned short* qws = (unsigned short*)(ws + OFF_QWS);
  unsigned short* kws = (unsigned short*)(ws + OFF_KWS);
  unsigned short* vtw = (unsigned short*)(ws + OFF_VTWS);
  unsigned short* ows = (unsigned short*)(ws + OFF_OWS);
  int* flags = (int*)(ws + OFF_FLAG);

  hipMemsetAsync(flags, 0, 4, stream);
  cvt_all<<<12296, 256, 0, stream>>>(x, y, Wq, Wk, Wv, Wp, pad, tmask, ws, flags);

  q_gemm<<<dim3(64, 8), 256, 0, stream>>>(ybf, wqb, qws);
  kv_gemm<<<dim3(64, 8), 256, 0, stream>>>(xbf, wkb, wvb, kws, vtw);

  attn_kernel<<<dim3(64, 8), 512, 0, stream>>>(qws, kws, vtw, ows, pad, tmask, flags);

  gemm_p<<<dim3(64, 8), 256, 0, stream>>>(ows, wpb, (float*)d_out, bp);
}

// Round 13
// 183.726 us; speedup vs baseline: 1.1580x; 1.0387x over previous
//
#include <hip/hip_runtime.h>
#include <hip/hip_bf16.h>
#include <stdint.h>
#include <stddef.h>

// MultiHA: y@Wq^T -> q; x@Wk^T -> k; x@Wv^T -> v; causal softmax attn; @Wp^T + bp
// B=4 S=2048 D=1024 NH=16 HS=64. All GEMM/attn compute in bf16 MFMA, f32 accum.

typedef __attribute__((ext_vector_type(4))) float f32x4;
typedef __attribute__((ext_vector_type(8))) short s16x8;
typedef __attribute__((ext_vector_type(4))) float float4v;
typedef __attribute__((ext_vector_type(4))) int i32x4;
typedef __attribute__((ext_vector_type(2))) unsigned int u32x2;

#define DEV __device__ __forceinline__

constexpr int Bsz = 4, Sseq = 2048, Dm = 1024, NHn = 16, HSn = 64;
// fold 1/sqrt(HS) * log2(e) into Wq so attention softmax runs in exp2 domain
constexpr float QSCALE = 0.125f * 1.4426950408889634f;

// ---- workspace layout (bytes) ----
constexpr size_t SZ_BF_XY = (size_t)Bsz * Sseq * Dm * 2;  // 16 MiB
constexpr size_t SZ_W     = (size_t)Dm * Dm * 2;          // 2 MiB
constexpr size_t OFF_XBF  = 0;
constexpr size_t OFF_YBF  = OFF_XBF + SZ_BF_XY;
constexpr size_t OFF_WQ   = OFF_YBF + SZ_BF_XY;
constexpr size_t OFF_WK   = OFF_WQ + SZ_W;
constexpr size_t OFF_WV   = OFF_WK + SZ_W;
constexpr size_t OFF_WP   = OFF_WV + SZ_W;
constexpr size_t OFF_QWS  = OFF_WP + SZ_W;   // [BH][S][64] bf16
constexpr size_t OFF_KWS  = OFF_QWS + SZ_BF_XY;
constexpr size_t OFF_VTWS = OFF_KWS + SZ_BF_XY; // [BH][64][S] bf16 (V transposed)
constexpr size_t OFF_OWS  = OFF_VTWS + SZ_BF_XY; // attn out [B][S][D] bf16
constexpr size_t OFF_FLAG = OFF_OWS + SZ_BF_XY;

DEV unsigned short f2bf(float f) {
  union { float f; unsigned int u; } v; v.f = f;
  unsigned int r = (v.u + 0x7FFFu + ((v.u >> 16) & 1u)) >> 16;
  return (unsigned short)r;
}

DEV void gll16(const void* g, void* l) {
  __builtin_amdgcn_global_load_lds((const __attribute__((address_space(1))) unsigned int*)g,
                                   (__attribute__((address_space(3))) unsigned int*)l, 16, 0, 0);
}

DEV unsigned int cvtpk(float a, float b) {
  unsigned int r;
  asm("v_cvt_pk_bf16_f32 %0, %1, %2" : "=v"(r) : "v"(a), "v"(b));
  return r;
}

union U8 { s16x8 v; unsigned int u[4]; };

// ------ fused fp32->bf16 conversion of all inputs + pad/tmask triviality check ------
__global__ void cvt_all(const float* __restrict__ x, const float* __restrict__ y,
                        const float* __restrict__ Wq, const float* __restrict__ Wk,
                        const float* __restrict__ Wv, const float* __restrict__ Wp,
                        const int* __restrict__ pad, const int* __restrict__ tmask,
                        char* __restrict__ ws, int* __restrict__ flags) {
  const int blk = blockIdx.x;
  if (blk >= 10240) {
    int bad = 0;
    if (blk < 10248) { // pad: 8192 ints, 4 per thread
      const i32x4 v = ((const i32x4*)pad)[(blk - 10240) * 256 + threadIdx.x];
      bad = (v[0] == 0) | (v[1] == 0) | (v[2] == 0) | (v[3] == 0);
    } else { // tmask: 4M ints, 8 per thread
      const i32x4* tp = (const i32x4*)tmask + ((size_t)(blk - 10248) * 256 + threadIdx.x) * 2;
      i32x4 v0 = tp[0], v1 = tp[1];
      bad = (v0[0] == 0) | (v0[1] == 0) | (v0[2] == 0) | (v0[3] == 0) |
            (v1[0] == 0) | (v1[1] == 0) | (v1[2] == 0) | (v1[3] == 0);
    }
    if (__builtin_amdgcn_ballot_w64(bad) != 0 && (threadIdx.x & 63) == 0)
      atomicOr(flags, 1);
    return;
  }
  const float* src;
  unsigned short* dst;
  int b8;
  float scale = 1.f;
  if (blk < 4096)      { src = x;  dst = (unsigned short*)(ws + OFF_XBF); b8 = blk; }
  else if (blk < 8192) { src = y;  dst = (unsigned short*)(ws + OFF_YBF); b8 = blk - 4096; }
  else if (blk < 8704) { src = Wq; dst = (unsigned short*)(ws + OFF_WQ);  b8 = blk - 8192; scale = QSCALE; }
  else if (blk < 9216) { src = Wk; dst = (unsigned short*)(ws + OFF_WK);  b8 = blk - 8704; }
  else if (blk < 9728) { src = Wv; dst = (unsigned short*)(ws + OFF_WV);  b8 = blk - 9216; }
  else                 { src = Wp; dst = (unsigned short*)(ws + OFF_WP);  b8 = blk - 9728; }
  const size_t i = (size_t)b8 * 256 + threadIdx.x;
  const float4v* s = (const float4v*)src + i * 2;
  float4v a = s[0], b = s[1];
  s16x8 o;
  o[0] = (short)f2bf(a[0] * scale); o[1] = (short)f2bf(a[1] * scale);
  o[2] = (short)f2bf(a[2] * scale); o[3] = (short)f2bf(a[3] * scale);
  o[4] = (short)f2bf(b[0] * scale); o[5] = (short)f2bf(b[1] * scale);
  o[6] = (short)f2bf(b[2] * scale); o[7] = (short)f2bf(b[3] * scale);
  *(s16x8*)(dst + i * 8) = o;
}

// ---------------- Q projection GEMM (2-phase double-buffered staging) ----------------
__global__ __launch_bounds__(256) void q_gemm(const unsigned short* __restrict__ A,
                                              const unsigned short* __restrict__ W,
                                              unsigned short* __restrict__ outb) {
  constexpr int K = 1024;
  __shared__ unsigned short sm[2][8192]; // [buf][lA 4096 | lB 4096]
  const int tid = threadIdx.x;
  const int w = tid >> 6, lane = tid & 63, lo = lane & 15, hi = lane >> 4;
  const int wm = w >> 1, wn = w & 1;
  const int m0 = blockIdx.x * 128, n0 = blockIdx.y * 128;
  f32x4 acc[4][4] = {};

  auto stage = [&](int buf, int k0) {
#pragma unroll
    for (int h = 0; h < 2; ++h) {
      int c = w * 64 + h * 256 + lane;
      gll16(A + (size_t)(m0 + (c >> 2)) * K + k0 + (c & 3) * 8, &sm[buf][0] + (size_t)(w * 64 + h * 256) * 8);
      gll16(W + (size_t)(n0 + (c >> 2)) * K + k0 + (c & 3) * 8, &sm[buf][4096] + (size_t)(w * 64 + h * 256) * 8);
    }
  };

  stage(0, 0);
  __syncthreads(); // drains vmcnt -> buf0 ready
  for (int t = 0; t < 32; ++t) {
    if (t < 31) stage((t + 1) & 1, (t + 1) * 32); // issue next tile early
    const unsigned short* lA = &sm[t & 1][0];
    const unsigned short* lB = &sm[t & 1][4096];
    s16x8 af[4], bfr[4];
#pragma unroll
    for (int mi = 0; mi < 4; ++mi) af[mi] = *(const s16x8*)&lA[(wm * 64 + mi * 16 + lo) * 32 + hi * 8];
#pragma unroll
    for (int ni = 0; ni < 4; ++ni) bfr[ni] = *(const s16x8*)&lB[(wn * 64 + ni * 16 + lo) * 32 + hi * 8];
#pragma unroll
    for (int mi = 0; mi < 4; ++mi)
#pragma unroll
      for (int ni = 0; ni < 4; ++ni)
        acc[mi][ni] = __builtin_amdgcn_mfma_f32_16x16x32_bf16(af[mi], bfr[ni], acc[mi][ni], 0, 0, 0);
    __syncthreads(); // readers done + next-tile loads drained
  }
#pragma unroll
  for (int mi = 0; mi < 4; ++mi)
#pragma unroll
    for (int ni = 0; ni < 4; ++ni)
#pragma unroll
      for (int j = 0; j < 4; ++j) {
        int m = m0 + wm * 64 + mi * 16 + hi * 4 + j;
        int n = n0 + wn * 64 + ni * 16 + lo;
        int b = m >> 11, s = m & 2047, hh = n >> 6, e = n & 63;
        outb[((size_t)(b * NHn + hh) * Sseq + s) * HSn + e] = f2bf(acc[mi][ni][j]);
      }
}

// -------- merged K+V projection GEMM (shared x staging, 2-phase double-buffer) --------
__global__ __launch_bounds__(256, 2) void kv_gemm(const unsigned short* __restrict__ A,
                                                  const unsigned short* __restrict__ Wk,
                                                  const unsigned short* __restrict__ Wv,
                                                  unsigned short* __restrict__ kws,
                                                  unsigned short* __restrict__ vtw) {
  constexpr int K = 1024;
  __shared__ unsigned short sm[2][12288]; // [buf][lA | lBk | lBv]; epilogue reuses flat
  const int tid = threadIdx.x;
  const int w = tid >> 6, lane = tid & 63, lo = lane & 15, hi = lane >> 4;
  const int wm = w >> 1, wn = w & 1;
  const int m0 = blockIdx.x * 128, n0 = blockIdx.y * 128;
  f32x4 acck[4][4] = {}, accv[4][4] = {};

  auto stage = [&](int buf, int k0) {
#pragma unroll
    for (int h = 0; h < 2; ++h) {
      int c = w * 64 + h * 256 + lane;
      size_t roff = (size_t)(c >> 2) * K + k0 + (c & 3) * 8;
      size_t loff = (size_t)(w * 64 + h * 256) * 8;
      gll16(A + (size_t)m0 * K + roff, &sm[buf][0] + loff);
      gll16(Wk + (size_t)n0 * K + roff, &sm[buf][4096] + loff);
      gll16(Wv + (size_t)n0 * K + roff, &sm[buf][8192] + loff);
    }
  };

  stage(0, 0);
  __syncthreads();
  for (int t = 0; t < 32; ++t) {
    if (t < 31) stage((t + 1) & 1, (t + 1) * 32);
    const unsigned short* lA = &sm[t & 1][0];
    const unsigned short* lBk = &sm[t & 1][4096];
    const unsigned short* lBv = &sm[t & 1][8192];
    s16x8 af[4], bfk[4], bfv[4];
#pragma unroll
    for (int mi = 0; mi < 4; ++mi) af[mi] = *(const s16x8*)&lA[(wm * 64 + mi * 16 + lo) * 32 + hi * 8];
#pragma unroll
    for (int ni = 0; ni < 4; ++ni) {
      bfk[ni] = *(const s16x8*)&lBk[(wn * 64 + ni * 16 + lo) * 32 + hi * 8];
      bfv[ni] = *(const s16x8*)&lBv[(wn * 64 + ni * 16 + lo) * 32 + hi * 8];
    }
#pragma unroll
    for (int mi = 0; mi < 4; ++mi)
#pragma unroll
      for (int ni = 0; ni < 4; ++ni) {
        acck[mi][ni] = __builtin_amdgcn_mfma_f32_16x16x32_bf16(af[mi], bfk[ni], acck[mi][ni], 0, 0, 0);
        accv[mi][ni] = __builtin_amdgcn_mfma_f32_16x16x32_bf16(af[mi], bfv[ni], accv[mi][ni], 0, 0, 0);
      }
    __syncthreads();
  }

  // K epilogue: direct global stores
#pragma unroll
  for (int mi = 0; mi < 4; ++mi)
#pragma unroll
    for (int ni = 0; ni < 4; ++ni)
#pragma unroll
      for (int j = 0; j < 4; ++j) {
        int m = m0 + wm * 64 + mi * 16 + hi * 4 + j;
        int n = n0 + wn * 64 + ni * 16 + lo;
        int b = m >> 11, s = m & 2047, hh = n >> 6, e = n & 63;
        kws[((size_t)(b * NHn + hh) * Sseq + s) * HSn + e] = f2bf(acck[mi][ni][j]);
      }
  // V epilogue: LDS transpose (reuses sm flat: needs 17408 shorts < 24576)
  unsigned short* tp = &sm[0][0];
  __syncthreads();
#pragma unroll
  for (int mi = 0; mi < 4; ++mi)
#pragma unroll
    for (int ni = 0; ni < 4; ++ni)
#pragma unroll
      for (int j = 0; j < 4; ++j) {
        int ml = wm * 64 + mi * 16 + hi * 4 + j;
        int nl = wn * 64 + ni * 16 + lo;
        tp[(size_t)nl * 136 + ml] = f2bf(accv[mi][ni][j]);
      }
  __syncthreads();
  int nl = tid >> 1, half = tid & 1;
  int b = m0 >> 11, hh = (n0 + nl) >> 6, e = (n0 + nl) & 63;
  unsigned short* dst = vtw + ((size_t)(b * NHn + hh) * HSn + e) * Sseq + (m0 & 2047) + half * 64;
#pragma unroll
  for (int i = 0; i < 8; ++i)
    *(s16x8*)(dst + i * 8) = *(const s16x8*)&tp[(size_t)nl * 136 + half * 64 + i * 8];
}

// ---------------- final projection GEMM (2-phase): fp32 out [M][1024] + bias ----------
__global__ __launch_bounds__(256) void gemm_p(const unsigned short* __restrict__ A,
                                              const unsigned short* __restrict__ W,
                                              float* __restrict__ outf,
                                              const float* __restrict__ bias) {
  constexpr int K = 1024;
  __shared__ unsigned short sm[2][8192];
  const int tid = threadIdx.x;
  const int w = tid >> 6, lane = tid & 63, lo = lane & 15, hi = lane >> 4;
  const int wm = w >> 1, wn = w & 1;
  const int m0 = blockIdx.x * 128, n0 = blockIdx.y * 128;
  f32x4 acc[4][4] = {};

  auto stage = [&](int buf, int k0) {
#pragma unroll
    for (int h = 0; h < 2; ++h) {
      int c = w * 64 + h * 256 + lane;
      gll16(A + (size_t)(m0 + (c >> 2)) * K + k0 + (c & 3) * 8, &sm[buf][0] + (size_t)(w * 64 + h * 256) * 8);
      gll16(W + (size_t)(n0 + (c >> 2)) * K + k0 + (c & 3) * 8, &sm[buf][4096] + (size_t)(w * 64 + h * 256) * 8);
    }
  };

  stage(0, 0);
  __syncthreads();
  for (int t = 0; t < 32; ++t) {
    if (t < 31) stage((t + 1) & 1, (t + 1) * 32);
    const unsigned short* lA = &sm[t & 1][0];
    const unsigned short* lB = &sm[t & 1][4096];
    s16x8 af[4], bfr[4];
#pragma unroll
    for (int mi = 0; mi < 4; ++mi) af[mi] = *(const s16x8*)&lA[(wm * 64 + mi * 16 + lo) * 32 + hi * 8];
#pragma unroll
    for (int ni = 0; ni < 4; ++ni) bfr[ni] = *(const s16x8*)&lB[(wn * 64 + ni * 16 + lo) * 32 + hi * 8];
#pragma unroll
    for (int mi = 0; mi < 4; ++mi)
#pragma unroll
      for (int ni = 0; ni < 4; ++ni)
        acc[mi][ni] = __builtin_amdgcn_mfma_f32_16x16x32_bf16(af[mi], bfr[ni], acc[mi][ni], 0, 0, 0);
    __syncthreads();
  }
  float bv[4];
#pragma unroll
  for (int ni = 0; ni < 4; ++ni) bv[ni] = bias[n0 + wn * 64 + ni * 16 + lo];
#pragma unroll
  for (int mi = 0; mi < 4; ++mi)
#pragma unroll
    for (int ni = 0; ni < 4; ++ni)
#pragma unroll
      for (int j = 0; j < 4; ++j) {
        int m = m0 + wm * 64 + mi * 16 + hi * 4 + j;
        int n = n0 + wn * 64 + ni * 16 + lo;
        outf[(size_t)m * 1024 + n] = acc[mi][ni][j] + bv[ni];
      }
}

// ---------------- flash attention (8-wave, permuted-K, zero-LDS P path) ----------------
// R12 structure + R13 change: K rows staged in bit-permuted order
//   storage row s holds logical K row L(s) = ((s&0x1C)<<1) | ((s&0x20)>>3) | (s&3)
// so the QK^T output slot (t,hi,j) holds logical kpos 32(t&1)+8hi+4(t>>1)+j, and the
// PV B-fragment pf[kk] (kpos 32kk+8hi+0..7, col q=lo) is a pure REGISTER rearrangement
// of the packed P values: pf[kk] = {pk[kk][0], pk[kk][1], pk[kk+2][0], pk[kk+2][1]}.
// The per-unit P LDS round-trip (4 ds_write_b64 + 2 ds_read_b128 + lgkm wait) is gone.
// Defer-max (thr=11, exp2 domain) + l via ones-MFMA as verified in R9.
DEV void attn_unit16(const unsigned short* __restrict__ kbc,
                     const unsigned short* __restrict__ vbc,
                     const s16x8 (&qf)[2], f32x4 (&oacc)[4], f32x4& lacc,
                     float& mrun, const s16x8& ones,
                     int k0, int qw0, int lo, int hi, int b,
                     const int* __restrict__ pad, const int* __restrict__ tmask,
                     bool trivial) {
  if (k0 > qw0 + 15) return; // wave-uniform: tile entirely above this wave's rows

  // S^T = K Q^T (operand-swapped; K rows permuted in LDS)
  f32x4 st[4];
#pragma unroll
  for (int t = 0; t < 4; ++t) {
    f32x4 z = {0.f, 0.f, 0.f, 0.f};
#pragma unroll
    for (int kk = 0; kk < 2; ++kk) {
      s16x8 kfr = *(const s16x8*)&kbc[(t * 16 + lo) * 72 + kk * 32 + hi * 8];
      z = __builtin_amdgcn_mfma_f32_16x16x32_bf16(kfr, qf[kk], z, 0, 0, 0);
    }
    st[t] = z;
  }
  const int qg = qw0 + lo;
  const int kgb = k0 + hi * 8; // logical kpos base for this lane's slots
  if (k0 + 63 > qw0) { // diagonal tiles: causal mask (logical kpos > q)
#pragma unroll
    for (int t = 0; t < 4; ++t)
#pragma unroll
      for (int j = 0; j < 4; ++j) {
        int kg = kgb + ((t & 1) << 5) + ((t >> 1) << 2) + j;
        if (kg > qg) st[t][j] = -3e38f;
      }
  }
  if (!trivial) { // general pad/time masks (not hit for all-ones inputs)
#pragma unroll
    for (int t = 0; t < 4; ++t)
#pragma unroll
      for (int j = 0; j < 4; ++j) {
        int kg = kgb + ((t & 1) << 5) + ((t >> 1) << 2) + j;
        if (!pad[b * Sseq + kg] || !tmask[(size_t)qg * Sseq + kg]) st[t][j] = -3e38f;
      }
  }
  // tile max for this lane's q-column (lane-local + 2 shuffles over hi-groups)
  float m0v = fmaxf(fmaxf(st[0][0], st[0][1]), fmaxf(st[0][2], st[0][3]));
  float m1v = fmaxf(fmaxf(st[1][0], st[1][1]), fmaxf(st[1][2], st[1][3]));
  float m2v = fmaxf(fmaxf(st[2][0], st[2][1]), fmaxf(st[2][2], st[2][3]));
  float m3v = fmaxf(fmaxf(st[3][0], st[3][1]), fmaxf(st[3][2], st[3][3]));
  float mx = fmaxf(fmaxf(m0v, m1v), fmaxf(m2v, m3v));
  mx = fmaxf(mx, __shfl_xor(mx, 16, 64));
  mx = fmaxf(mx, __shfl_xor(mx, 32, 64));
  // defer-max: only rescale when the bound would be exceeded (P <= 2^11 otherwise)
  if (!__all(mx <= mrun + 11.f)) {
    const float mnew = fmaxf(mrun, mx);
    const float al = __builtin_amdgcn_exp2f(mrun - mnew);
    mrun = mnew;
#pragma unroll
    for (int et = 0; et < 4; ++et) oacc[et] *= al;
    lacc *= al;
  }
  // P = exp2(S - mrun), packed to bf16 pairs in registers
  unsigned int pk[4][2];
#pragma unroll
  for (int t = 0; t < 4; ++t) {
    float p0 = __builtin_amdgcn_exp2f(st[t][0] - mrun);
    float p1 = __builtin_amdgcn_exp2f(st[t][1] - mrun);
    float p2 = __builtin_amdgcn_exp2f(st[t][2] - mrun);
    float p3 = __builtin_amdgcn_exp2f(st[t][3] - mrun);
    pk[t][0] = cvtpk(p0, p1);
    pk[t][1] = cvtpk(p2, p3);
  }
  // assemble PV B-fragments in registers (kpos = kk*32 + hi*8 + 0..7, col q = lo)
  U8 pf0, pf1;
  pf0.u[0] = pk[0][0]; pf0.u[1] = pk[0][1]; pf0.u[2] = pk[2][0]; pf0.u[3] = pk[2][1];
  pf1.u[0] = pk[1][0]; pf1.u[1] = pk[1][1]; pf1.u[2] = pk[3][0]; pf1.u[3] = pk[3][1];
  // O^T += V^T P^T ; l += ones . P (all rows of lacc equal l[q])
#pragma unroll
  for (int et = 0; et < 4; ++et) {
    s16x8 vf0 = *(const s16x8*)&vbc[(et * 16 + lo) * 72 + hi * 8];
    s16x8 vf1 = *(const s16x8*)&vbc[(et * 16 + lo) * 72 + 32 + hi * 8];
    oacc[et] = __builtin_amdgcn_mfma_f32_16x16x32_bf16(vf0, pf0.v, oacc[et], 0, 0, 0);
    oacc[et] = __builtin_amdgcn_mfma_f32_16x16x32_bf16(vf1, pf1.v, oacc[et], 0, 0, 0);
  }
  lacc = __builtin_amdgcn_mfma_f32_16x16x32_bf16(ones, pf0.v, lacc, 0, 0, 0);
  lacc = __builtin_amdgcn_mfma_f32_16x16x32_bf16(ones, pf1.v, lacc, 0, 0, 0);
}

// normalize by l (lane-local) and write O via per-wave LDS transpose (16 rows)
DEV void attn_epi16(f32x4 (&oacc)[4], float lrun,
                    unsigned short* __restrict__ scr,
                    unsigned short* __restrict__ O, int b, int hh, int qw0,
                    int lane, int lo, int hi) {
  const float inv = 1.f / lrun;
#pragma unroll
  for (int et = 0; et < 4; ++et) {
    f32x4 o = oacc[et] * inv;
    u32x2 d = {cvtpk(o[0], o[1]), cvtpk(o[2], o[3])};
    *(u32x2*)&scr[lo * 72 + et * 16 + hi * 4] = d;
  }
  int q = lane >> 2, seg = lane & 3;
  unsigned short* dst = O + ((size_t)b * Sseq + qw0 + q) * Dm + hh * HSn + seg * 16;
  *(s16x8*)dst = *(const s16x8*)&scr[q * 72 + seg * 16];
  *(s16x8*)(dst + 8) = *(const s16x8*)&scr[q * 72 + seg * 16 + 8];
}

__global__ __launch_bounds__(512, 4) void attn_kernel(const unsigned short* __restrict__ Q,
                                                      const unsigned short* __restrict__ Kg,
                                                      const unsigned short* __restrict__ Vt,
                                                      unsigned short* __restrict__ O,
                                                      const int* __restrict__ pad,
                                                      const int* __restrict__ tmask,
                                                      const int* __restrict__ flags) {
  __shared__ unsigned short kb[2][64 * 72];   // 18.0 KiB (epilogue reuses as scratch)
  __shared__ unsigned short vb[2][64 * 72];   // 18.0 KiB

  const int ip = blockIdx.y, bh = blockIdx.x; // bh fastest -> same-bh blocks on one XCD
  const int b = bh >> 4, hh = bh & 15;
  const int tid = threadIdx.x, w = tid >> 6, lane = tid & 63, lo = lane & 15, hi = lane >> 4;
  const int qtA = ip, qtB = 15 - ip;
  const int qw0A = qtA * 128 + w * 16, qw0B = qtB * 128 + w * 16;
  const int ktA = 2 * qtA + 1;       // last K-tile index tile A needs (any wave)
  const int ktmax = 2 * qtB + 2;     // number of K-tiles tile B needs
  const bool trivial = flags[0] == 0;

  const unsigned short* Qb = Q + (size_t)bh * Sseq * HSn;
  const unsigned short* Kb = Kg + (size_t)bh * Sseq * HSn;
  const unsigned short* Vb = Vt + (size_t)bh * HSn * Sseq;

  // Q fragments (B-operand of swapped QK^T)
  s16x8 qfA[2], qfB[2];
#pragma unroll
  for (int kk = 0; kk < 2; ++kk) {
    qfA[kk] = *(const s16x8*)&Qb[(size_t)(qw0A + lo) * HSn + kk * 32 + hi * 8];
    qfB[kk] = *(const s16x8*)&Qb[(size_t)(qw0B + lo) * HSn + kk * 32 + hi * 8];
  }

  s16x8 ones;
#pragma unroll
  for (int j = 0; j < 8; ++j) ones[j] = (short)0x3F80; // bf16 1.0

  f32x4 oaccA[4] = {}, oaccB[4] = {};
  f32x4 laccA = {}, laccB = {};
  float mrunA = -3e38f, mrunB = -3e38f;

  // staging: waves 0-3 handle K (bit-permuted row order), waves 4-7 handle V
  const int shalf = tid >> 8, st_t = tid & 255;
  const int sr = st_t >> 2, sc = (st_t & 3) * 16;
  // logical K row for storage row sr: L = [s4 s3 s2 | s5 | s1 s0]
  const int srK = ((sr & 0x1C) << 1) | ((sr & 0x20) >> 3) | (sr & 3);

  // prologue: stage kt=0 into buffer 0
  s16x8 r0, r1;
  if (shalf == 0) {
    const unsigned short* gk = Kb + (size_t)srK * HSn + sc;
    r0 = *(const s16x8*)gk; r1 = *(const s16x8*)(gk + 8);
    *(s16x8*)&kb[0][sr * 72 + sc] = r0; *(s16x8*)&kb[0][sr * 72 + sc + 8] = r1;
  } else {
    const unsigned short* gv = Vb + (size_t)sr * Sseq + sc;
    r0 = *(const s16x8*)gv; r1 = *(const s16x8*)(gv + 8);
    *(s16x8*)&vb[0][sr * 72 + sc] = r0; *(s16x8*)&vb[0][sr * 72 + sc + 8] = r1;
  }
  __syncthreads();

  for (int kt = 0; kt < ktmax; ++kt) {
    const int cur = kt & 1, k0 = kt * 64;
    const bool pre = (kt + 1 < ktmax);
    if (pre) { // issue next-tile loads early; latency hides under compute
      const int k1 = k0 + 64;
      if (shalf == 0) {
        const unsigned short* gk = Kb + (size_t)(k1 + srK) * HSn + sc;
        r0 = *(const s16x8*)gk; r1 = *(const s16x8*)(gk + 8);
      } else {
        const unsigned short* gv = Vb + (size_t)sr * Sseq + k1 + sc;
        r0 = *(const s16x8*)gv; r1 = *(const s16x8*)(gv + 8);
      }
    }
    const unsigned short* kbc = kb[cur];
    const unsigned short* vbc = vb[cur];
    if (kt <= ktA)
      attn_unit16(kbc, vbc, qfA, oaccA, laccA, mrunA, ones,
                  k0, qw0A, lo, hi, b, pad, tmask, trivial);
    attn_unit16(kbc, vbc, qfB, oaccB, laccB, mrunB, ones,
                k0, qw0B, lo, hi, b, pad, tmask, trivial);
    if (pre) { // write-late into the other buffer
      const int nb = cur ^ 1;
      if (shalf == 0) {
        *(s16x8*)&kb[nb][sr * 72 + sc] = r0; *(s16x8*)&kb[nb][sr * 72 + sc + 8] = r1;
      } else {
        *(s16x8*)&vb[nb][sr * 72 + sc] = r0; *(s16x8*)&vb[nb][sr * 72 + sc + 8] = r1;
      }
    }
    __syncthreads();
  }

  // epilogue: per-wave scratch carved out of kb (all compute on kb finished above)
  unsigned short* scr = (unsigned short*)kb + (size_t)w * 1152;
  attn_epi16(oaccA, laccA[0], scr, O, b, hh, qw0A, lane, lo, hi);
  attn_epi16(oaccB, laccB[0], scr, O, b, hh, qw0B, lane, lo, hi);
}

extern "C" void kernel_launch(void* const* d_in, const int* in_sizes, int n_in,
                              void* d_out, int out_size, void* d_ws, size_t ws_size,
                              hipStream_t stream) {
  const float* x = (const float*)d_in[0];
  const float* y = (const float*)d_in[1];
  const int* pad = (const int*)d_in[2];
  const int* tmask = (const int*)d_in[3];
  const float* Wq = (const float*)d_in[4];
  const float* Wk = (const float*)d_in[5];
  const float* Wv = (const float*)d_in[6];
  const float* Wp = (const float*)d_in[7];
  const float* bp = (const float*)d_in[8];

  char* ws = (char*)d_ws;
  unsigned short* xbf = (unsigned short*)(ws + OFF_XBF);
  unsigned short* ybf = (unsigned short*)(ws + OFF_YBF);
  unsigned short* wqb = (unsigned short*)(ws + OFF_WQ);
  unsigned short* wkb = (unsigned short*)(ws + OFF_WK);
  unsigned short* wvb = (unsigned short*)(ws + OFF_WV);
  unsigned short* wpb = (unsigned short*)(ws + OFF_WP);
  unsigned short* qws = (unsigned short*)(ws + OFF_QWS);
  unsigned short* kws = (unsigned short*)(ws + OFF_KWS);
  unsigned short* vtw = (unsigned short*)(ws + OFF_VTWS);
  unsigned short* ows = (unsigned short*)(ws + OFF_OWS);
  int* flags = (int*)(ws + OFF_FLAG);

  hipMemsetAsync(flags, 0, 4, stream);
  cvt_all<<<12296, 256, 0, stream>>>(x, y, Wq, Wk, Wv, Wp, pad, tmask, ws, flags);

  q_gemm<<<dim3(64, 8), 256, 0, stream>>>(ybf, wqb, qws);
  kv_gemm<<<dim3(64, 8), 256, 0, stream>>>(xbf, wkb, wvb, kws, vtw);

  attn_kernel<<<dim3(64, 8), 512, 0, stream>>>(qws, kws, vtw, ows, pad, tmask, flags);

  gemm_p<<<dim3(64, 8), 256, 0, stream>>>(ows, wpb, (float*)d_out, bp);
}

// Round 16
// 183.614 us; speedup vs baseline: 1.1587x; 1.0006x over previous
//
#include <hip/hip_runtime.h>
#include <hip/hip_bf16.h>
#include <stdint.h>
#include <stddef.h>

// MultiHA: y@Wq^T -> q; x@Wk^T -> k; x@Wv^T -> v; causal softmax attn; @Wp^T + bp
// B=4 S=2048 D=1024 NH=16 HS=64. All GEMM/attn compute in bf16 MFMA, f32 accum.

typedef __attribute__((ext_vector_type(4))) float f32x4;
typedef __attribute__((ext_vector_type(8))) short s16x8;
typedef __attribute__((ext_vector_type(4))) float float4v;
typedef __attribute__((ext_vector_type(4))) int i32x4;
typedef __attribute__((ext_vector_type(2))) unsigned int u32x2;

#define DEV __device__ __forceinline__

constexpr int Bsz = 4, Sseq = 2048, Dm = 1024, NHn = 16, HSn = 64;
// fold 1/sqrt(HS) * log2(e) into Wq so attention softmax runs in exp2 domain
constexpr float QSCALE = 0.125f * 1.4426950408889634f;

// ---- workspace layout (bytes) ----
constexpr size_t SZ_BF_XY = (size_t)Bsz * Sseq * Dm * 2;  // 16 MiB
constexpr size_t SZ_W     = (size_t)Dm * Dm * 2;          // 2 MiB
constexpr size_t OFF_XBF  = 0;
constexpr size_t OFF_YBF  = OFF_XBF + SZ_BF_XY;
constexpr size_t OFF_WQ   = OFF_YBF + SZ_BF_XY;
constexpr size_t OFF_WK   = OFF_WQ + SZ_W;
constexpr size_t OFF_WV   = OFF_WK + SZ_W;
constexpr size_t OFF_WP   = OFF_WV + SZ_W;
constexpr size_t OFF_QWS  = OFF_WP + SZ_W;   // [BH][S][64] bf16
constexpr size_t OFF_KWS  = OFF_QWS + SZ_BF_XY;
constexpr size_t OFF_VTWS = OFF_KWS + SZ_BF_XY; // [BH][64][S] bf16 (V transposed)
constexpr size_t OFF_OWS  = OFF_VTWS + SZ_BF_XY; // attn out [B][S][D] bf16
constexpr size_t OFF_FLAG = OFF_OWS + SZ_BF_XY;

DEV unsigned short f2bf(float f) {
  union { float f; unsigned int u; } v; v.f = f;
  unsigned int r = (v.u + 0x7FFFu + ((v.u >> 16) & 1u)) >> 16;
  return (unsigned short)r;
}

DEV void gll16(const void* g, void* l) {
  __builtin_amdgcn_global_load_lds((const __attribute__((address_space(1))) unsigned int*)g,
                                   (__attribute__((address_space(3))) unsigned int*)l, 16, 0, 0);
}

DEV unsigned int cvtpk(float a, float b) {
  unsigned int r;
  asm("v_cvt_pk_bf16_f32 %0, %1, %2" : "=v"(r) : "v"(a), "v"(b));
  return r;
}

union U8 { s16x8 v; unsigned int u[4]; };

// ------ fused fp32->bf16 conversion of all inputs + pad/tmask triviality check ------
__global__ void cvt_all(const float* __restrict__ x, const float* __restrict__ y,
                        const float* __restrict__ Wq, const float* __restrict__ Wk,
                        const float* __restrict__ Wv, const float* __restrict__ Wp,
                        const int* __restrict__ pad, const int* __restrict__ tmask,
                        char* __restrict__ ws, int* __restrict__ flags) {
  const int blk = blockIdx.x;
  if (blk >= 10240) {
    int bad = 0;
    if (blk < 10248) { // pad: 8192 ints, 4 per thread
      const i32x4 v = ((const i32x4*)pad)[(blk - 10240) * 256 + threadIdx.x];
      bad = (v[0] == 0) | (v[1] == 0) | (v[2] == 0) | (v[3] == 0);
    } else { // tmask: 4M ints, 8 per thread
      const i32x4* tp = (const i32x4*)tmask + ((size_t)(blk - 10248) * 256 + threadIdx.x) * 2;
      i32x4 v0 = tp[0], v1 = tp[1];
      bad = (v0[0] == 0) | (v0[1] == 0) | (v0[2] == 0) | (v0[3] == 0) |
            (v1[0] == 0) | (v1[1] == 0) | (v1[2] == 0) | (v1[3] == 0);
    }
    if (__builtin_amdgcn_ballot_w64(bad) != 0 && (threadIdx.x & 63) == 0)
      atomicOr(flags, 1);
    return;
  }
  const float* src;
  unsigned short* dst;
  int b8;
  float scale = 1.f;
  if (blk < 4096)      { src = x;  dst = (unsigned short*)(ws + OFF_XBF); b8 = blk; }
  else if (blk < 8192) { src = y;  dst = (unsigned short*)(ws + OFF_YBF); b8 = blk - 4096; }
  else if (blk < 8704) { src = Wq; dst = (unsigned short*)(ws + OFF_WQ);  b8 = blk - 8192; scale = QSCALE; }
  else if (blk < 9216) { src = Wk; dst = (unsigned short*)(ws + OFF_WK);  b8 = blk - 8704; }
  else if (blk < 9728) { src = Wv; dst = (unsigned short*)(ws + OFF_WV);  b8 = blk - 9216; }
  else                 { src = Wp; dst = (unsigned short*)(ws + OFF_WP);  b8 = blk - 9728; }
  const size_t i = (size_t)b8 * 256 + threadIdx.x;
  const float4v* s = (const float4v*)src + i * 2;
  float4v a = s[0], b = s[1];
  s16x8 o;
  o[0] = (short)f2bf(a[0] * scale); o[1] = (short)f2bf(a[1] * scale);
  o[2] = (short)f2bf(a[2] * scale); o[3] = (short)f2bf(a[3] * scale);
  o[4] = (short)f2bf(b[0] * scale); o[5] = (short)f2bf(b[1] * scale);
  o[6] = (short)f2bf(b[2] * scale); o[7] = (short)f2bf(b[3] * scale);
  *(s16x8*)(dst + i * 8) = o;
}

// ---------------- Q projection GEMM (2-phase double-buffered staging) ----------------
__global__ __launch_bounds__(256) void q_gemm(const unsigned short* __restrict__ A,
                                              const unsigned short* __restrict__ W,
                                              unsigned short* __restrict__ outb) {
  constexpr int K = 1024;
  __shared__ unsigned short sm[2][8192]; // [buf][lA 4096 | lB 4096]
  const int tid = threadIdx.x;
  const int w = tid >> 6, lane = tid & 63, lo = lane & 15, hi = lane >> 4;
  const int wm = w >> 1, wn = w & 1;
  const int m0 = blockIdx.x * 128, n0 = blockIdx.y * 128;
  f32x4 acc[4][4] = {};

  auto stage = [&](int buf, int k0) {
#pragma unroll
    for (int h = 0; h < 2; ++h) {
      int c = w * 64 + h * 256 + lane;
      gll16(A + (size_t)(m0 + (c >> 2)) * K + k0 + (c & 3) * 8, &sm[buf][0] + (size_t)(w * 64 + h * 256) * 8);
      gll16(W + (size_t)(n0 + (c >> 2)) * K + k0 + (c & 3) * 8, &sm[buf][4096] + (size_t)(w * 64 + h * 256) * 8);
    }
  };

  stage(0, 0);
  __syncthreads(); // drains vmcnt -> buf0 ready
  for (int t = 0; t < 32; ++t) {
    if (t < 31) stage((t + 1) & 1, (t + 1) * 32); // issue next tile early
    const unsigned short* lA = &sm[t & 1][0];
    const unsigned short* lB = &sm[t & 1][4096];
    s16x8 af[4], bfr[4];
#pragma unroll
    for (int mi = 0; mi < 4; ++mi) af[mi] = *(const s16x8*)&lA[(wm * 64 + mi * 16 + lo) * 32 + hi * 8];
#pragma unroll
    for (int ni = 0; ni < 4; ++ni) bfr[ni] = *(const s16x8*)&lB[(wn * 64 + ni * 16 + lo) * 32 + hi * 8];
#pragma unroll
    for (int mi = 0; mi < 4; ++mi)
#pragma unroll
      for (int ni = 0; ni < 4; ++ni)
        acc[mi][ni] = __builtin_amdgcn_mfma_f32_16x16x32_bf16(af[mi], bfr[ni], acc[mi][ni], 0, 0, 0);
    __syncthreads(); // readers done + next-tile loads drained
  }
#pragma unroll
  for (int mi = 0; mi < 4; ++mi)
#pragma unroll
    for (int ni = 0; ni < 4; ++ni)
#pragma unroll
      for (int j = 0; j < 4; ++j) {
        int m = m0 + wm * 64 + mi * 16 + hi * 4 + j;
        int n = n0 + wn * 64 + ni * 16 + lo;
        int b = m >> 11, s = m & 2047, hh = n >> 6, e = n & 63;
        outb[((size_t)(b * NHn + hh) * Sseq + s) * HSn + e] = f2bf(acc[mi][ni][j]);
      }
}

// -------- merged K+V projection GEMM (shared x staging, 2-phase double-buffer) --------
__global__ __launch_bounds__(256, 2) void kv_gemm(const unsigned short* __restrict__ A,
                                                  const unsigned short* __restrict__ Wk,
                                                  const unsigned short* __restrict__ Wv,
                                                  unsigned short* __restrict__ kws,
                                                  unsigned short* __restrict__ vtw) {
  constexpr int K = 1024;
  __shared__ unsigned short sm[2][12288]; // [buf][lA | lBk | lBv]; epilogue reuses flat
  const int tid = threadIdx.x;
  const int w = tid >> 6, lane = tid & 63, lo = lane & 15, hi = lane >> 4;
  const int wm = w >> 1, wn = w & 1;
  const int m0 = blockIdx.x * 128, n0 = blockIdx.y * 128;
  f32x4 acck[4][4] = {}, accv[4][4] = {};

  auto stage = [&](int buf, int k0) {
#pragma unroll
    for (int h = 0; h < 2; ++h) {
      int c = w * 64 + h * 256 + lane;
      size_t roff = (size_t)(c >> 2) * K + k0 + (c & 3) * 8;
      size_t loff = (size_t)(w * 64 + h * 256) * 8;
      gll16(A + (size_t)m0 * K + roff, &sm[buf][0] + loff);
      gll16(Wk + (size_t)n0 * K + roff, &sm[buf][4096] + loff);
      gll16(Wv + (size_t)n0 * K + roff, &sm[buf][8192] + loff);
    }
  };

  stage(0, 0);
  __syncthreads();
  for (int t = 0; t < 32; ++t) {
    if (t < 31) stage((t + 1) & 1, (t + 1) * 32);
    const unsigned short* lA = &sm[t & 1][0];
    const unsigned short* lBk = &sm[t & 1][4096];
    const unsigned short* lBv = &sm[t & 1][8192];
    s16x8 af[4], bfk[4], bfv[4];
#pragma unroll
    for (int mi = 0; mi < 4; ++mi) af[mi] = *(const s16x8*)&lA[(wm * 64 + mi * 16 + lo) * 32 + hi * 8];
#pragma unroll
    for (int ni = 0; ni < 4; ++ni) {
      bfk[ni] = *(const s16x8*)&lBk[(wn * 64 + ni * 16 + lo) * 32 + hi * 8];
      bfv[ni] = *(const s16x8*)&lBv[(wn * 64 + ni * 16 + lo) * 32 + hi * 8];
    }
#pragma unroll
    for (int mi = 0; mi < 4; ++mi)
#pragma unroll
      for (int ni = 0; ni < 4; ++ni) {
        acck[mi][ni] = __builtin_amdgcn_mfma_f32_16x16x32_bf16(af[mi], bfk[ni], acck[mi][ni], 0, 0, 0);
        accv[mi][ni] = __builtin_amdgcn_mfma_f32_16x16x32_bf16(af[mi], bfv[ni], accv[mi][ni], 0, 0, 0);
      }
    __syncthreads();
  }

  // K epilogue: direct global stores
#pragma unroll
  for (int mi = 0; mi < 4; ++mi)
#pragma unroll
    for (int ni = 0; ni < 4; ++ni)
#pragma unroll
      for (int j = 0; j < 4; ++j) {
        int m = m0 + wm * 64 + mi * 16 + hi * 4 + j;
        int n = n0 + wn * 64 + ni * 16 + lo;
        int b = m >> 11, s = m & 2047, hh = n >> 6, e = n & 63;
        kws[((size_t)(b * NHn + hh) * Sseq + s) * HSn + e] = f2bf(acck[mi][ni][j]);
      }
  // V epilogue: LDS transpose (reuses sm flat: needs 17408 shorts < 24576)
  unsigned short* tp = &sm[0][0];
  __syncthreads();
#pragma unroll
  for (int mi = 0; mi < 4; ++mi)
#pragma unroll
    for (int ni = 0; ni < 4; ++ni)
#pragma unroll
      for (int j = 0; j < 4; ++j) {
        int ml = wm * 64 + mi * 16 + hi * 4 + j;
        int nl = wn * 64 + ni * 16 + lo;
        tp[(size_t)nl * 136 + ml] = f2bf(accv[mi][ni][j]);
      }
  __syncthreads();
  int nl = tid >> 1, half = tid & 1;
  int b = m0 >> 11, hh = (n0 + nl) >> 6, e = (n0 + nl) & 63;
  unsigned short* dst = vtw + ((size_t)(b * NHn + hh) * HSn + e) * Sseq + (m0 & 2047) + half * 64;
#pragma unroll
  for (int i = 0; i < 8; ++i)
    *(s16x8*)(dst + i * 8) = *(const s16x8*)&tp[(size_t)nl * 136 + half * 64 + i * 8];
}

// ---------------- final projection GEMM (2-phase): fp32 out [M][1024] + bias ----------
__global__ __launch_bounds__(256) void gemm_p(const unsigned short* __restrict__ A,
                                              const unsigned short* __restrict__ W,
                                              float* __restrict__ outf,
                                              const float* __restrict__ bias) {
  constexpr int K = 1024;
  __shared__ unsigned short sm[2][8192];
  const int tid = threadIdx.x;
  const int w = tid >> 6, lane = tid & 63, lo = lane & 15, hi = lane >> 4;
  const int wm = w >> 1, wn = w & 1;
  const int m0 = blockIdx.x * 128, n0 = blockIdx.y * 128;
  f32x4 acc[4][4] = {};

  auto stage = [&](int buf, int k0) {
#pragma unroll
    for (int h = 0; h < 2; ++h) {
      int c = w * 64 + h * 256 + lane;
      gll16(A + (size_t)(m0 + (c >> 2)) * K + k0 + (c & 3) * 8, &sm[buf][0] + (size_t)(w * 64 + h * 256) * 8);
      gll16(W + (size_t)(n0 + (c >> 2)) * K + k0 + (c & 3) * 8, &sm[buf][4096] + (size_t)(w * 64 + h * 256) * 8);
    }
  };

  stage(0, 0);
  __syncthreads();
  for (int t = 0; t < 32; ++t) {
    if (t < 31) stage((t + 1) & 1, (t + 1) * 32);
    const unsigned short* lA = &sm[t & 1][0];
    const unsigned short* lB = &sm[t & 1][4096];
    s16x8 af[4], bfr[4];
#pragma unroll
    for (int mi = 0; mi < 4; ++mi) af[mi] = *(const s16x8*)&lA[(wm * 64 + mi * 16 + lo) * 32 + hi * 8];
#pragma unroll
    for (int ni = 0; ni < 4; ++ni) bfr[ni] = *(const s16x8*)&lB[(wn * 64 + ni * 16 + lo) * 32 + hi * 8];
#pragma unroll
    for (int mi = 0; mi < 4; ++mi)
#pragma unroll
      for (int ni = 0; ni < 4; ++ni)
        acc[mi][ni] = __builtin_amdgcn_mfma_f32_16x16x32_bf16(af[mi], bfr[ni], acc[mi][ni], 0, 0, 0);
    __syncthreads();
  }
  float bv[4];
#pragma unroll
  for (int ni = 0; ni < 4; ++ni) bv[ni] = bias[n0 + wn * 64 + ni * 16 + lo];
#pragma unroll
  for (int mi = 0; mi < 4; ++mi)
#pragma unroll
    for (int ni = 0; ni < 4; ++ni)
#pragma unroll
      for (int j = 0; j < 4; ++j) {
        int m = m0 + wm * 64 + mi * 16 + hi * 4 + j;
        int n = n0 + wn * 64 + ni * 16 + lo;
        outf[(size_t)m * 1024 + n] = acc[mi][ni][j] + bv[ni];
      }
}

// ---------------- flash attention (R13-verified, + T5 setprio around MFMA) ------------
// K rows staged bit-permuted: storage row s holds logical ((s&0x1C)<<1)|((s&0x20)>>3)|(s&3).
// QK^T slot (t,hi,j) = logical kpos 32(t&1)+8hi+4(t>>1)+j; PV B-fragment is a pure
// register rearrangement of packed P (zero-LDS P path). Defer-max (thr=11, exp2 domain)
// + l via ones-MFMA. setprio(1) wraps MFMA clusters (T5, +4-7% attn per m191).
DEV void attn_unit16(const unsigned short* __restrict__ kbc,
                     const unsigned short* __restrict__ vbc,
                     const s16x8 (&qf)[2], f32x4 (&oacc)[4], f32x4& lacc,
                     float& mrun, const s16x8& ones,
                     int k0, int qw0, int lo, int hi, int b,
                     const int* __restrict__ pad, const int* __restrict__ tmask,
                     bool trivial) {
  if (k0 > qw0 + 15) return; // wave-uniform: tile entirely above this wave's rows

  // S^T = K Q^T (operand-swapped; K rows permuted in LDS)
  f32x4 st[4];
  __builtin_amdgcn_s_setprio(1);
#pragma unroll
  for (int t = 0; t < 4; ++t) {
    f32x4 z = {0.f, 0.f, 0.f, 0.f};
#pragma unroll
    for (int kk = 0; kk < 2; ++kk) {
      s16x8 kfr = *(const s16x8*)&kbc[(t * 16 + lo) * 72 + kk * 32 + hi * 8];
      z = __builtin_amdgcn_mfma_f32_16x16x32_bf16(kfr, qf[kk], z, 0, 0, 0);
    }
    st[t] = z;
  }
  __builtin_amdgcn_s_setprio(0);
  const int qg = qw0 + lo;
  const int kgb = k0 + hi * 8; // logical kpos base for this lane's slots
  if (k0 + 63 > qw0) { // diagonal tiles: causal mask (logical kpos > q)
#pragma unroll
    for (int t = 0; t < 4; ++t)
#pragma unroll
      for (int j = 0; j < 4; ++j) {
        int kg = kgb + ((t & 1) << 5) + ((t >> 1) << 2) + j;
        if (kg > qg) st[t][j] = -3e38f;
      }
  }
  if (!trivial) { // general pad/time masks (not hit for all-ones inputs)
#pragma unroll
    for (int t = 0; t < 4; ++t)
#pragma unroll
      for (int j = 0; j < 4; ++j) {
        int kg = kgb + ((t & 1) << 5) + ((t >> 1) << 2) + j;
        if (!pad[b * Sseq + kg] || !tmask[(size_t)qg * Sseq + kg]) st[t][j] = -3e38f;
      }
  }
  // tile max for this lane's q-column (lane-local + 2 shuffles over hi-groups)
  float m0v = fmaxf(fmaxf(st[0][0], st[0][1]), fmaxf(st[0][2], st[0][3]));
  float m1v = fmaxf(fmaxf(st[1][0], st[1][1]), fmaxf(st[1][2], st[1][3]));
  float m2v = fmaxf(fmaxf(st[2][0], st[2][1]), fmaxf(st[2][2], st[2][3]));
  float m3v = fmaxf(fmaxf(st[3][0], st[3][1]), fmaxf(st[3][2], st[3][3]));
  float mx = fmaxf(fmaxf(m0v, m1v), fmaxf(m2v, m3v));
  mx = fmaxf(mx, __shfl_xor(mx, 16, 64));
  mx = fmaxf(mx, __shfl_xor(mx, 32, 64));
  // defer-max: only rescale when the bound would be exceeded (P <= 2^11 otherwise)
  if (!__all(mx <= mrun + 11.f)) {
    const float mnew = fmaxf(mrun, mx);
    const float al = __builtin_amdgcn_exp2f(mrun - mnew);
    mrun = mnew;
#pragma unroll
    for (int et = 0; et < 4; ++et) oacc[et] *= al;
    lacc *= al;
  }
  // P = exp2(S - mrun), packed to bf16 pairs in registers
  unsigned int pk[4][2];
#pragma unroll
  for (int t = 0; t < 4; ++t) {
    float p0 = __builtin_amdgcn_exp2f(st[t][0] - mrun);
    float p1 = __builtin_amdgcn_exp2f(st[t][1] - mrun);
    float p2 = __builtin_amdgcn_exp2f(st[t][2] - mrun);
    float p3 = __builtin_amdgcn_exp2f(st[t][3] - mrun);
    pk[t][0] = cvtpk(p0, p1);
    pk[t][1] = cvtpk(p2, p3);
  }
  // assemble PV B-fragments in registers (kpos = kk*32 + hi*8 + 0..7, col q = lo)
  U8 pf0, pf1;
  pf0.u[0] = pk[0][0]; pf0.u[1] = pk[0][1]; pf0.u[2] = pk[2][0]; pf0.u[3] = pk[2][1];
  pf1.u[0] = pk[1][0]; pf1.u[1] = pk[1][1]; pf1.u[2] = pk[3][0]; pf1.u[3] = pk[3][1];
  // O^T += V^T P^T ; l += ones . P (all rows of lacc equal l[q])
  __builtin_amdgcn_s_setprio(1);
#pragma unroll
  for (int et = 0; et < 4; ++et) {
    s16x8 vf0 = *(const s16x8*)&vbc[(et * 16 + lo) * 72 + hi * 8];
    s16x8 vf1 = *(const s16x8*)&vbc[(et * 16 + lo) * 72 + 32 + hi * 8];
    oacc[et] = __builtin_amdgcn_mfma_f32_16x16x32_bf16(vf0, pf0.v, oacc[et], 0, 0, 0);
    oacc[et] = __builtin_amdgcn_mfma_f32_16x16x32_bf16(vf1, pf1.v, oacc[et], 0, 0, 0);
  }
  lacc = __builtin_amdgcn_mfma_f32_16x16x32_bf16(ones, pf0.v, lacc, 0, 0, 0);
  lacc = __builtin_amdgcn_mfma_f32_16x16x32_bf16(ones, pf1.v, lacc, 0, 0, 0);
  __builtin_amdgcn_s_setprio(0);
}

// normalize by l (lane-local) and write O via per-wave LDS transpose (16 rows)
DEV void attn_epi16(f32x4 (&oacc)[4], float lrun,
                    unsigned short* __restrict__ scr,
                    unsigned short* __restrict__ O, int b, int hh, int qw0,
                    int lane, int lo, int hi) {
  const float inv = 1.f / lrun;
#pragma unroll
  for (int et = 0; et < 4; ++et) {
    f32x4 o = oacc[et] * inv;
    u32x2 d = {cvtpk(o[0], o[1]), cvtpk(o[2], o[3])};
    *(u32x2*)&scr[lo * 72 + et * 16 + hi * 4] = d;
  }
  int q = lane >> 2, seg = lane & 3;
  unsigned short* dst = O + ((size_t)b * Sseq + qw0 + q) * Dm + hh * HSn + seg * 16;
  *(s16x8*)dst = *(const s16x8*)&scr[q * 72 + seg * 16];
  *(s16x8*)(dst + 8) = *(const s16x8*)&scr[q * 72 + seg * 16 + 8];
}

__global__ __launch_bounds__(512, 4) void attn_kernel(const unsigned short* __restrict__ Q,
                                                      const unsigned short* __restrict__ Kg,
                                                      const unsigned short* __restrict__ Vt,
                                                      unsigned short* __restrict__ O,
                                                      const int* __restrict__ pad,
                                                      const int* __restrict__ tmask,
                                                      const int* __restrict__ flags) {
  __shared__ unsigned short kb[2][64 * 72];   // 18.0 KiB (epilogue reuses as scratch)
  __shared__ unsigned short vb[2][64 * 72];   // 18.0 KiB

  const int ip = blockIdx.y, bh = blockIdx.x; // bh fastest -> same-bh blocks on one XCD
  const int b = bh >> 4, hh = bh & 15;
  const int tid = threadIdx.x, w = tid >> 6, lane = tid & 63, lo = lane & 15, hi = lane >> 4;
  const int qtA = ip, qtB = 15 - ip;
  const int qw0A = qtA * 128 + w * 16, qw0B = qtB * 128 + w * 16;
  const int ktA = 2 * qtA + 1;       // last K-tile index tile A needs (any wave)
  const int ktmax = 2 * qtB + 2;     // number of K-tiles tile B needs
  const bool trivial = flags[0] == 0;

  const unsigned short* Qb = Q + (size_t)bh * Sseq * HSn;
  const unsigned short* Kb = Kg + (size_t)bh * Sseq * HSn;
  const unsigned short* Vb = Vt + (size_t)bh * HSn * Sseq;

  // Q fragments (B-operand of swapped QK^T)
  s16x8 qfA[2], qfB[2];
#pragma unroll
  for (int kk = 0; kk < 2; ++kk) {
    qfA[kk] = *(const s16x8*)&Qb[(size_t)(qw0A + lo) * HSn + kk * 32 + hi * 8];
    qfB[kk] = *(const s16x8*)&Qb[(size_t)(qw0B + lo) * HSn + kk * 32 + hi * 8];
  }

  s16x8 ones;
#pragma unroll
  for (int j = 0; j < 8; ++j) ones[j] = (short)0x3F80; // bf16 1.0

  f32x4 oaccA[4] = {}, oaccB[4] = {};
  f32x4 laccA = {}, laccB = {};
  float mrunA = -3e38f, mrunB = -3e38f;

  // staging: waves 0-3 handle K (bit-permuted row order), waves 4-7 handle V
  const int shalf = tid >> 8, st_t = tid & 255;
  const int sr = st_t >> 2, sc = (st_t & 3) * 16;
  // logical K row for storage row sr: L = [s4 s3 s2 | s5 | s1 s0]
  const int srK = ((sr & 0x1C) << 1) | ((sr & 0x20) >> 3) | (sr & 3);

  // prologue: stage kt=0 into buffer 0
  s16x8 r0, r1;
  if (shalf == 0) {
    const unsigned short* gk = Kb + (size_t)srK * HSn + sc;
    r0 = *(const s16x8*)gk; r1 = *(const s16x8*)(gk + 8);
    *(s16x8*)&kb[0][sr * 72 + sc] = r0; *(s16x8*)&kb[0][sr * 72 + sc + 8] = r1;
  } else {
    const unsigned short* gv = Vb + (size_t)sr * Sseq + sc;
    r0 = *(const s16x8*)gv; r1 = *(const s16x8*)(gv + 8);
    *(s16x8*)&vb[0][sr * 72 + sc] = r0; *(s16x8*)&vb[0][sr * 72 + sc + 8] = r1;
  }
  __syncthreads();

  for (int kt = 0; kt < ktmax; ++kt) {
    const int cur = kt & 1, k0 = kt * 64;
    const bool pre = (kt + 1 < ktmax);
    if (pre) { // issue next-tile loads early; latency hides under compute
      const int k1 = k0 + 64;
      if (shalf == 0) {
        const unsigned short* gk = Kb + (size_t)(k1 + srK) * HSn + sc;
        r0 = *(const s16x8*)gk; r1 = *(const s16x8*)(gk + 8);
      } else {
        const unsigned short* gv = Vb + (size_t)sr * Sseq + k1 + sc;
        r0 = *(const s16x8*)gv; r1 = *(const s16x8*)(gv + 8);
      }
    }
    const unsigned short* kbc = kb[cur];
    const unsigned short* vbc = vb[cur];
    if (kt <= ktA)
      attn_unit16(kbc, vbc, qfA, oaccA, laccA, mrunA, ones,
                  k0, qw0A, lo, hi, b, pad, tmask, trivial);
    attn_unit16(kbc, vbc, qfB, oaccB, laccB, mrunB, ones,
                k0, qw0B, lo, hi, b, pad, tmask, trivial);
    if (pre) { // write-late into the other buffer
      const int nb = cur ^ 1;
      if (shalf == 0) {
        *(s16x8*)&kb[nb][sr * 72 + sc] = r0; *(s16x8*)&kb[nb][sr * 72 + sc + 8] = r1;
      } else {
        *(s16x8*)&vb[nb][sr * 72 + sc] = r0; *(s16x8*)&vb[nb][sr * 72 + sc + 8] = r1;
      }
    }
    __syncthreads();
  }

  // epilogue: per-wave scratch carved out of kb (all compute on kb finished above)
  unsigned short* scr = (unsigned short*)kb + (size_t)w * 1152;
  attn_epi16(oaccA, laccA[0], scr, O, b, hh, qw0A, lane, lo, hi);
  attn_epi16(oaccB, laccB[0], scr, O, b, hh, qw0B, lane, lo, hi);
}

extern "C" void kernel_launch(void* const* d_in, const int* in_sizes, int n_in,
                              void* d_out, int out_size, void* d_ws, size_t ws_size,
                              hipStream_t stream) {
  const float* x = (const float*)d_in[0];
  const float* y = (const float*)d_in[1];
  const int* pad = (const int*)d_in[2];
  const int* tmask = (const int*)d_in[3];
  const float* Wq = (const float*)d_in[4];
  const float* Wk = (const float*)d_in[5];
  const float* Wv = (const float*)d_in[6];
  const float* Wp = (const float*)d_in[7];
  const float* bp = (const float*)d_in[8];

  char* ws = (char*)d_ws;
  unsigned short* xbf = (unsigned short*)(ws + OFF_XBF);
  unsigned short* ybf = (unsigned short*)(ws + OFF_YBF);
  unsigned short* wqb = (unsigned short*)(ws + OFF_WQ);
  unsigned short* wkb = (unsigned short*)(ws + OFF_WK);
  unsigned short* wvb = (unsigned short*)(ws + OFF_WV);
  unsigned short* wpb = (unsigned short*)(ws + OFF_WP);
  unsigned short* qws = (unsigned short*)(ws + OFF_QWS);
  unsigned short* kws = (unsigned short*)(ws + OFF_KWS);
  unsigned short* vtw = (unsigned short*)(ws + OFF_VTWS);
  unsigned short* ows = (unsigned short*)(ws + OFF_OWS);
  int* flags = (int*)(ws + OFF_FLAG);

  hipMemsetAsync(flags, 0, 4, stream);
  cvt_all<<<12296, 256, 0, stream>>>(x, y, Wq, Wk, Wv, Wp, pad, tmask, ws, flags);

  q_gemm<<<dim3(64, 8), 256, 0, stream>>>(ybf, wqb, qws);
  kv_gemm<<<dim3(64, 8), 256, 0, stream>>>(xbf, wkb, wvb, kws, vtw);

  attn_kernel<<<dim3(64, 8), 512, 0, stream>>>(qws, kws, vtw, ows, pad, tmask, flags);

  gemm_p<<<dim3(64, 8), 256, 0, stream>>>(ows, wpb, (float*)d_out, bp);
}